// Round 2
// baseline (2313.922 us; speedup 1.0000x reference)
//
#include <hip/hip_runtime.h>
#include <math.h>

#define BB 4
#define LL 2048
#define DM 1024
#define DI 2048
#define DS 16
#define DTR 64

typedef unsigned short bf16;

__device__ inline float b2f(bf16 u) { return __uint_as_float(((unsigned)u) << 16); }
__device__ inline bf16 f2b(float f) {
    unsigned u = __float_as_uint(f);
    u += 0x7FFF + ((u >> 16) & 1);   // round-to-nearest-even
    return (bf16)(u >> 16);
}

__device__ inline float4 ld4(const float* p) { return *(const float4*)p; }
__device__ inline float4 ld4(const bf16* p) {
    ushort4 v = *(const ushort4*)p;
    return make_float4(b2f(v.x), b2f(v.y), b2f(v.z), b2f(v.w));
}
__device__ inline void st1(float* p, float v) { *p = v; }
__device__ inline void st1(bf16* p, float v) { *p = f2b(v); }

// ---------------- LayerNorm: one block per row (1024 cols, 256 thr x4) -------
__global__ __launch_bounds__(256) void ln_kernel(const float* __restrict__ x,
    const float* __restrict__ w, const float* __restrict__ b,
    float* __restrict__ xn)
{
    int row = blockIdx.x;
    int tid = threadIdx.x;
    const float* xr = x + (size_t)row * DM;
    float4 v = *(const float4*)(xr + tid * 4);
    float s1 = v.x + v.y + v.z + v.w;
    float s2 = v.x * v.x + v.y * v.y + v.z * v.z + v.w * v.w;
    #pragma unroll
    for (int o = 32; o > 0; o >>= 1) {
        s1 += __shfl_xor(s1, o);
        s2 += __shfl_xor(s2, o);
    }
    __shared__ float r1[4], r2[4];
    __shared__ float smu, srs;
    int wv = tid >> 6;
    if ((tid & 63) == 0) { r1[wv] = s1; r2[wv] = s2; }
    __syncthreads();
    if (tid == 0) {
        float t1 = r1[0] + r1[1] + r1[2] + r1[3];
        float t2 = r2[0] + r2[1] + r2[2] + r2[3];
        float mu = t1 * (1.0f / DM);
        float var = t2 * (1.0f / DM) - mu * mu;
        smu = mu;
        srs = rsqrtf(var + 1e-5f);
    }
    __syncthreads();
    float mu = smu, rs = srs;
    float4 wv4 = *(const float4*)(w + tid * 4);
    float4 bv4 = *(const float4*)(b + tid * 4);
    float4 o;
    o.x = (v.x - mu) * rs * wv4.x + bv4.x;
    o.y = (v.y - mu) * rs * wv4.y + bv4.y;
    o.z = (v.z - mu) * rs * wv4.z + bv4.z;
    o.w = (v.w - mu) * rs * wv4.w + bv4.w;
    *(float4*)(xn + (size_t)row * DM + tid * 4) = o;
}

// ---------------- Tiled f32-compute GEMM, NT: C[m,n] = sum_k A[m,k]*B[n,k] ---
// EPI 0: none.  EPI 1: C = softplus(acc + aux[n]).  EPI 2: C = acc + aux[m*ldc+n].
template<int EPI, typename TA, typename TB, typename TC>
__global__ __launch_bounds__(256) void gemm_nt(
    const TA* __restrict__ A, int lda,
    const TB* __restrict__ B, int ldb,
    TC* __restrict__ C, int ldc,
    int M, int N, int K,
    const float* __restrict__ aux)
{
    __shared__ float As[16][64];
    __shared__ float Bs[16][64];
    int tid = threadIdx.x;
    int m0 = blockIdx.y * 64, n0 = blockIdx.x * 64;
    int lr = tid >> 2;           // 0..63: tile row for loads
    int lc = (tid & 3) * 4;      // k offset 0,4,8,12
    int tm = tid >> 4;           // 0..15
    int tn = tid & 15;           // 0..15
    float acc[4][4] = {};
    for (int kt = 0; kt < K; kt += 16) {
        float4 av = ld4(A + (size_t)(m0 + lr) * lda + kt + lc);
        float4 bv = make_float4(0.f, 0.f, 0.f, 0.f);
        if (n0 + lr < N)
            bv = ld4(B + (size_t)(n0 + lr) * ldb + kt + lc);
        As[lc + 0][lr] = av.x; As[lc + 1][lr] = av.y;
        As[lc + 2][lr] = av.z; As[lc + 3][lr] = av.w;
        Bs[lc + 0][lr] = bv.x; Bs[lc + 1][lr] = bv.y;
        Bs[lc + 2][lr] = bv.z; Bs[lc + 3][lr] = bv.w;
        __syncthreads();
        #pragma unroll
        for (int k = 0; k < 16; k++) {
            float4 a4 = *(const float4*)&As[k][tm * 4];
            float4 b4 = *(const float4*)&Bs[k][tn * 4];
            float am[4] = {a4.x, a4.y, a4.z, a4.w};
            float bn[4] = {b4.x, b4.y, b4.z, b4.w};
            #pragma unroll
            for (int i = 0; i < 4; i++)
                #pragma unroll
                for (int j = 0; j < 4; j++)
                    acc[i][j] = fmaf(am[i], bn[j], acc[i][j]);
        }
        __syncthreads();
    }
    #pragma unroll
    for (int i = 0; i < 4; i++) {
        int m = m0 + tm * 4 + i;
        #pragma unroll
        for (int j = 0; j < 4; j++) {
            int n = n0 + tn * 4 + j;
            if (n >= N) continue;
            float v = acc[i][j];
            if (EPI == 1) {
                v += aux[n];
                v = (v > 20.f) ? v : log1pf(__expf(v));
            } else if (EPI == 2) {
                v += aux[(size_t)m * ldc + n];
            }
            st1(&C[(size_t)m * ldc + n], v);
        }
    }
}

// ---------------- Depthwise causal conv (4 taps) + SiLU ----------------------
// x_in = xz[:, 0:DI] (bf16, row stride 2*DI); out xc [B*L, DI] bf16
__global__ __launch_bounds__(256) void conv_silu_kernel(
    const bf16* __restrict__ xz, const float* __restrict__ cw,
    const float* __restrict__ cb, bf16* __restrict__ xc)
{
    int idx = blockIdx.x * 256 + threadIdx.x;   // B*L*DI/4 threads
    int d4 = idx & (DI / 4 - 1);                // 0..511
    int bl = idx >> 9;                          // 0..8191
    int l = bl & (LL - 1);
    int d0 = d4 * 4;
    float4 bias = *(const float4*)(cb + d0);
    float acc[4] = {bias.x, bias.y, bias.z, bias.w};
    #pragma unroll
    for (int k = 0; k < 4; k++) {
        int lp = l - 3 + k;
        if (lp < 0) continue;
        float4 xv = ld4(xz + (size_t)(bl - 3 + k) * (2 * DI) + d0);
        acc[0] = fmaf(xv.x, cw[(d0 + 0) * 4 + k], acc[0]);
        acc[1] = fmaf(xv.y, cw[(d0 + 1) * 4 + k], acc[1]);
        acc[2] = fmaf(xv.z, cw[(d0 + 2) * 4 + k], acc[2]);
        acc[3] = fmaf(xv.w, cw[(d0 + 3) * 4 + k], acc[3]);
    }
    ushort4 o;
    o.x = f2b(acc[0] / (1.f + __expf(-acc[0])));
    o.y = f2b(acc[1] / (1.f + __expf(-acc[1])));
    o.z = f2b(acc[2] / (1.f + __expf(-acc[2])));
    o.w = f2b(acc[3] / (1.f + __expf(-acc[3])));
    *(ushort4*)(xc + (size_t)bl * DI + d0) = o;
}

// ---------------- Selective scan -------------------------------------------
// Block: (b, 16 channels). Thread: (channel dg, state s). h kept in register.
// Reads dt (bf16) from dty, u (bf16) from xc, B/C (f32) from xdbl, z (bf16)
// from xz cols DI.. . Writes y = (scan + u*Dp) * silu(z) in-place into dty.
__global__ __launch_bounds__(256) void scan_kernel(
    const float* __restrict__ xdbl,   // [B*L, 96] f32
    bf16* __restrict__ dty,           // [B*L, DI] dt in / y out
    const bf16* __restrict__ xc,      // [B*L, DI]  (u)
    const bf16* __restrict__ xz,      // [B*L, 2*DI] (z at +DI)
    const float* __restrict__ A_log,  // [DI, DS]
    const float* __restrict__ Dp)     // [DI]
{
    const int TC = 64;
    int b = blockIdx.x >> 7;          // / (DI/16)
    int dblk = blockIdx.x & 127;
    int d0 = dblk * 16;
    int tid = threadIdx.x;
    int s = tid & 15;
    int dg = tid >> 4;                // 0..15
    int d = d0 + dg;
    float Ads = -__expf(A_log[(size_t)d * DS + s]);
    float h = 0.f;
    __shared__ float sdt[TC][16], su[TC][16], sB[TC][16], sC[TC][16], sy[TC][16];
    const size_t rowbase = (size_t)b * LL;
    int wi = tid >> 2;                // 0..63
    int wj = (tid & 3) * 4;           // 0,4,8,12
    float4 dpv = *(const float4*)(Dp + d0 + wj);

    for (int t0 = 0; t0 < LL; t0 += TC) {
        // ---- load dt, u (4 bf16 per thread each) ----
        {
            size_t g = (rowbase + t0 + wi) * (size_t)DI + d0 + wj;
            *(float4*)&sdt[wi][wj] = ld4(dty + g);
            *(float4*)&su[wi][wj]  = ld4(xc + g);
        }
        // ---- load B, C (f32) ----
        #pragma unroll
        for (int r = 0; r < 4; r++) {
            int i = (tid >> 4) + r * 16;
            size_t g = (rowbase + t0 + i) * 96;
            sB[i][s] = xdbl[g + DTR + s];
            sC[i][s] = xdbl[g + DTR + DS + s];
        }
        __syncthreads();
        // ---- sequential scan over the chunk ----
        for (int i = 0; i < TC; i++) {
            float dtv = sdt[i][dg];
            float uv  = su[i][dg];
            float bv  = sB[i][s];
            float cv  = sC[i][s];
            float dA = __expf(dtv * Ads);
            h = dA * h + dtv * uv * bv;
            float yp = h * cv;
            yp += __shfl_xor(yp, 1);
            yp += __shfl_xor(yp, 2);
            yp += __shfl_xor(yp, 4);
            yp += __shfl_xor(yp, 8);
            if (s == 0) sy[i][dg] = yp;
        }
        __syncthreads();
        // ---- write y = (scan + u*Dp) * silu(z), in-place over dt ----
        {
            size_t g  = (rowbase + t0 + wi) * (size_t)DI + d0 + wj;
            size_t gz = (rowbase + t0 + wi) * (size_t)(2 * DI) + DI + d0 + wj;
            float4 zv = ld4(xz + gz);
            float4 yv = *(const float4*)&sy[wi][wj];
            float4 uv = *(const float4*)&su[wi][wj];
            ushort4 o;
            o.x = f2b((yv.x + uv.x * dpv.x) * (zv.x / (1.f + __expf(-zv.x))));
            o.y = f2b((yv.y + uv.y * dpv.y) * (zv.y / (1.f + __expf(-zv.y))));
            o.z = f2b((yv.z + uv.z * dpv.z) * (zv.z / (1.f + __expf(-zv.z))));
            o.w = f2b((yv.w + uv.w * dpv.w) * (zv.w / (1.f + __expf(-zv.w))));
            *(ushort4*)(dty + g) = o;
        }
        __syncthreads();
    }
}

// ---------------------------------------------------------------------------
extern "C" void kernel_launch(void* const* d_in, const int* in_sizes, int n_in,
                              void* d_out, int out_size, void* d_ws, size_t ws_size,
                              hipStream_t stream)
{
    const float* x      = (const float*)d_in[0];
    const float* ln_w   = (const float*)d_in[1];
    const float* ln_b   = (const float*)d_in[2];
    const float* W_in   = (const float*)d_in[3];
    const float* conv_w = (const float*)d_in[4];
    const float* conv_b = (const float*)d_in[5];
    const float* W_x    = (const float*)d_in[6];
    const float* W_dt   = (const float*)d_in[7];
    const float* b_dt   = (const float*)d_in[8];
    const float* A_log  = (const float*)d_in[9];
    const float* Dp     = (const float*)d_in[10];
    const float* W_out  = (const float*)d_in[11];
    float* out = (float*)d_out;

    const size_t R = (size_t)BB * LL;   // 8192 rows

    // d_out (32 MB) doubles as scratch: xn f32 (phases 1-2), xc bf16 (3-5).
    float* xn = (float*)d_out;          // R*DM f32
    bf16*  xc = (bf16*)d_out;           // R*DI bf16 (same 32 MB)

    // ws: xz bf16 (64 MB) | dty bf16 (32 MB) | xdbl f32 (3 MB)  => ~99 MB
    bf16*  xz   = (bf16*)d_ws;                    // R * 2*DI
    bf16*  dty  = xz + R * 2 * DI;                // R * DI
    float* xdbl = (float*)(dty + R * DI);         // R * 96

    // 1. LayerNorm -> xn (in d_out)
    ln_kernel<<<(int)R, 256, 0, stream>>>(x, ln_w, ln_b, xn);

    // 2. in_proj: xz[8192,4096] = xn @ W_in^T   (bf16 out)
    gemm_nt<0><<<dim3(2 * DI / 64, R / 64), 256, 0, stream>>>(
        xn, DM, W_in, DM, xz, 2 * DI, (int)R, 2 * DI, DM, nullptr);

    // 3. conv + SiLU -> xc (in d_out; xn now dead)
    conv_silu_kernel<<<(int)(R * DI / 4 / 256), 256, 0, stream>>>(
        xz, conv_w, conv_b, xc);

    // 4a. x_proj: xdbl[8192,96] = xc @ W_x^T   (f32 out)
    gemm_nt<0><<<dim3(2, R / 64), 256, 0, stream>>>(
        xc, DI, W_x, DI, xdbl, 96, (int)R, 96, DI, nullptr);

    // 4b. dt = softplus(xdbl[:,:64] @ W_dt^T + b_dt) -> dty (bf16)
    gemm_nt<1><<<dim3(DI / 64, R / 64), 256, 0, stream>>>(
        xdbl, 96, W_dt, DTR, dty, DI, (int)R, DI, DTR, b_dt);

    // 5. selective scan + D-skip + z-gate (y overwrites dty)
    scan_kernel<<<BB * (DI / 16), 256, 0, stream>>>(
        xdbl, dty, xc, xz, A_log, Dp);

    // 6. out_proj + residual: out = y @ W_out^T + x  (overwrites d_out; xc dead)
    gemm_nt<2><<<dim3(DM / 64, R / 64), 256, 0, stream>>>(
        dty, DI, W_out, DI, out, DM, (int)R, DM, DI, x);
}

// Round 3
// 1076.344 us; speedup vs baseline: 2.1498x; 2.1498x over previous
//
#include <hip/hip_runtime.h>
#include <math.h>

#define BB 4
#define LL 2048
#define DM 1024
#define DI 2048
#define DS 16
#define DTR 64

typedef unsigned short bf16;
typedef __attribute__((ext_vector_type(8))) short bf16x8;
typedef __attribute__((ext_vector_type(4))) float f32x4;

__device__ inline float b2f(bf16 u) { return __uint_as_float(((unsigned)u) << 16); }
__device__ inline bf16 f2b(float f) {
    unsigned u = __float_as_uint(f);
    u += 0x7FFF + ((u >> 16) & 1);   // round-to-nearest-even
    return (bf16)(u >> 16);
}

__device__ inline float4 ld4(const float* p) { return *(const float4*)p; }
__device__ inline float4 ld4(const bf16* p) {
    ushort4 v = *(const ushort4*)p;
    return make_float4(b2f(v.x), b2f(v.y), b2f(v.z), b2f(v.w));
}
__device__ inline void st1(float* p, float v) { *p = v; }
__device__ inline void st1(bf16* p, float v) { *p = f2b(v); }

// async global->LDS, 16 bytes per lane; LDS dest = wave-uniform base + lane*16
__device__ inline void gld_lds16(const void* g, void* l) {
    __builtin_amdgcn_global_load_lds(
        (const __attribute__((address_space(1))) unsigned int*)g,
        (__attribute__((address_space(3))) unsigned int*)l, 16, 0, 0);
}

// ---------------- f32 -> bf16 convert (weights) ------------------------------
__global__ __launch_bounds__(256) void f2b_kernel(const float* __restrict__ in,
    bf16* __restrict__ out, int n4)
{
    int i = blockIdx.x * 256 + threadIdx.x;
    if (i >= n4) return;
    float4 v = *(const float4*)(in + (size_t)i * 4);
    ushort4 o = { f2b(v.x), f2b(v.y), f2b(v.z), f2b(v.w) };
    *(ushort4*)(out + (size_t)i * 4) = o;
}

// ---------------- LayerNorm: one block per row, bf16 out ---------------------
__global__ __launch_bounds__(256) void ln_kernel(const float* __restrict__ x,
    const float* __restrict__ w, const float* __restrict__ b,
    bf16* __restrict__ xn)
{
    int row = blockIdx.x;
    int tid = threadIdx.x;
    const float* xr = x + (size_t)row * DM;
    float4 v = *(const float4*)(xr + tid * 4);
    float s1 = v.x + v.y + v.z + v.w;
    float s2 = v.x * v.x + v.y * v.y + v.z * v.z + v.w * v.w;
    #pragma unroll
    for (int o = 32; o > 0; o >>= 1) {
        s1 += __shfl_xor(s1, o);
        s2 += __shfl_xor(s2, o);
    }
    __shared__ float r1[4], r2[4];
    __shared__ float smu, srs;
    int wv = tid >> 6;
    if ((tid & 63) == 0) { r1[wv] = s1; r2[wv] = s2; }
    __syncthreads();
    if (tid == 0) {
        float t1 = r1[0] + r1[1] + r1[2] + r1[3];
        float t2 = r2[0] + r2[1] + r2[2] + r2[3];
        float mu = t1 * (1.0f / DM);
        float var = t2 * (1.0f / DM) - mu * mu;
        smu = mu;
        srs = rsqrtf(var + 1e-5f);
    }
    __syncthreads();
    float mu = smu, rs = srs;
    float4 wv4 = *(const float4*)(w + tid * 4);
    float4 bv4 = *(const float4*)(b + tid * 4);
    ushort4 o;
    o.x = f2b((v.x - mu) * rs * wv4.x + bv4.x);
    o.y = f2b((v.y - mu) * rs * wv4.y + bv4.y);
    o.z = f2b((v.z - mu) * rs * wv4.z + bv4.z);
    o.w = f2b((v.w - mu) * rs * wv4.w + bv4.w);
    *(ushort4*)(xn + (size_t)row * DM + tid * 4) = o;
}

// ---------------- MFMA bf16 GEMM, NT: C[m,n] = sum_k A[m,k]*B[n,k] ----------
// 128x128 tile, BK=32, 4 waves each 64x64 (4x4 frags of 16x16x32 MFMA).
// EPI 0: plain store. EPI 2: C = acc + aux[m*ldc+n] (residual, f32 out).
template<int EPI, typename TC>
__global__ __launch_bounds__(256) void gemm_mfma(
    const bf16* __restrict__ A, int lda,
    const bf16* __restrict__ B, int ldb,
    TC* __restrict__ C, int ldc,
    int K, const float* __restrict__ aux)
{
    __shared__ bf16 As[128 * 32];
    __shared__ bf16 Bs[128 * 32];
    const int tid = threadIdx.x;
    const int lane = tid & 63;
    const int w = tid >> 6;            // wave 0..3
    const int wm = w >> 1, wn = w & 1; // 2x2 wave grid of 64x64
    const int m0 = blockIdx.y * 128, n0 = blockIdx.x * 128;

    const int srow = lane >> 2;        // staging: 16 rows per wave-instr
    const int schunk = (lane & 3) * 8; // 8 bf16 = 16 B per lane

    const int fm = lane & 15;          // fragment row (A/B operand)
    const int fq = lane >> 4;          // k-chunk 0..3 (8 elems each)

    f32x4 acc[4][4] = {};

    for (int kt = 0; kt < K; kt += 32) {
        #pragma unroll
        for (int i = 0; i < 2; i++) {
            int r0 = i * 64 + w * 16;  // wave-uniform LDS base row
            gld_lds16(A + (size_t)(m0 + r0 + srow) * lda + kt + schunk, &As[r0 * 32]);
            gld_lds16(B + (size_t)(n0 + r0 + srow) * ldb + kt + schunk, &Bs[r0 * 32]);
        }
        __syncthreads();
        bf16x8 af[4], bfr[4];
        #pragma unroll
        for (int i = 0; i < 4; i++) {
            af[i]  = *(const bf16x8*)&As[(wm * 64 + i * 16 + fm) * 32 + fq * 8];
            bfr[i] = *(const bf16x8*)&Bs[(wn * 64 + i * 16 + fm) * 32 + fq * 8];
        }
        #pragma unroll
        for (int i = 0; i < 4; i++)
            #pragma unroll
            for (int j = 0; j < 4; j++)
                acc[i][j] = __builtin_amdgcn_mfma_f32_16x16x32_bf16(
                    af[i], bfr[j], acc[i][j], 0, 0, 0);
        __syncthreads();
    }

    // C/D layout: col = lane&15, row = (lane>>4)*4 + r (within each 16x16 tile)
    #pragma unroll
    for (int i = 0; i < 4; i++) {
        #pragma unroll
        for (int r = 0; r < 4; r++) {
            int m = m0 + wm * 64 + i * 16 + fq * 4 + r;
            #pragma unroll
            for (int j = 0; j < 4; j++) {
                int n = n0 + wn * 64 + j * 16 + fm;
                float v = acc[i][j][r];
                if (EPI == 2) v += aux[(size_t)m * ldc + n];
                st1(&C[(size_t)m * ldc + n], v);
            }
        }
    }
}

// ---------------- Tiled f32-compute GEMM (small shapes), NT ------------------
// EPI 0: none.  EPI 1: C = softplus(acc + aux[n]).
template<int EPI, typename TA, typename TB, typename TC>
__global__ __launch_bounds__(256) void gemm_nt(
    const TA* __restrict__ A, int lda,
    const TB* __restrict__ B, int ldb,
    TC* __restrict__ C, int ldc,
    int M, int N, int K,
    const float* __restrict__ aux)
{
    __shared__ float As[16][64];
    __shared__ float Bs[16][64];
    int tid = threadIdx.x;
    int m0 = blockIdx.y * 64, n0 = blockIdx.x * 64;
    int lr = tid >> 2;
    int lc = (tid & 3) * 4;
    int tm = tid >> 4;
    int tn = tid & 15;
    float acc[4][4] = {};
    for (int kt = 0; kt < K; kt += 16) {
        float4 av = ld4(A + (size_t)(m0 + lr) * lda + kt + lc);
        float4 bv = make_float4(0.f, 0.f, 0.f, 0.f);
        if (n0 + lr < N)
            bv = ld4(B + (size_t)(n0 + lr) * ldb + kt + lc);
        As[lc + 0][lr] = av.x; As[lc + 1][lr] = av.y;
        As[lc + 2][lr] = av.z; As[lc + 3][lr] = av.w;
        Bs[lc + 0][lr] = bv.x; Bs[lc + 1][lr] = bv.y;
        Bs[lc + 2][lr] = bv.z; Bs[lc + 3][lr] = bv.w;
        __syncthreads();
        #pragma unroll
        for (int k = 0; k < 16; k++) {
            float4 a4 = *(const float4*)&As[k][tm * 4];
            float4 b4 = *(const float4*)&Bs[k][tn * 4];
            float am[4] = {a4.x, a4.y, a4.z, a4.w};
            float bn[4] = {b4.x, b4.y, b4.z, b4.w};
            #pragma unroll
            for (int i = 0; i < 4; i++)
                #pragma unroll
                for (int j = 0; j < 4; j++)
                    acc[i][j] = fmaf(am[i], bn[j], acc[i][j]);
        }
        __syncthreads();
    }
    #pragma unroll
    for (int i = 0; i < 4; i++) {
        int m = m0 + tm * 4 + i;
        #pragma unroll
        for (int j = 0; j < 4; j++) {
            int n = n0 + tn * 4 + j;
            if (n >= N) continue;
            float v = acc[i][j];
            if (EPI == 1) {
                v += aux[n];
                v = (v > 20.f) ? v : log1pf(__expf(v));
            }
            st1(&C[(size_t)m * ldc + n], v);
        }
    }
}

// ---------------- Depthwise causal conv (4 taps) + SiLU ----------------------
__global__ __launch_bounds__(256) void conv_silu_kernel(
    const bf16* __restrict__ xz, const float* __restrict__ cw,
    const float* __restrict__ cb, bf16* __restrict__ xc)
{
    int idx = blockIdx.x * 256 + threadIdx.x;
    int d4 = idx & (DI / 4 - 1);
    int bl = idx >> 9;
    int l = bl & (LL - 1);
    int d0 = d4 * 4;
    float4 bias = *(const float4*)(cb + d0);
    float acc[4] = {bias.x, bias.y, bias.z, bias.w};
    #pragma unroll
    for (int k = 0; k < 4; k++) {
        int lp = l - 3 + k;
        if (lp < 0) continue;
        float4 xv = ld4(xz + (size_t)(bl - 3 + k) * (2 * DI) + d0);
        acc[0] = fmaf(xv.x, cw[(d0 + 0) * 4 + k], acc[0]);
        acc[1] = fmaf(xv.y, cw[(d0 + 1) * 4 + k], acc[1]);
        acc[2] = fmaf(xv.z, cw[(d0 + 2) * 4 + k], acc[2]);
        acc[3] = fmaf(xv.w, cw[(d0 + 3) * 4 + k], acc[3]);
    }
    ushort4 o;
    o.x = f2b(acc[0] / (1.f + __expf(-acc[0])));
    o.y = f2b(acc[1] / (1.f + __expf(-acc[1])));
    o.z = f2b(acc[2] / (1.f + __expf(-acc[2])));
    o.w = f2b(acc[3] / (1.f + __expf(-acc[3])));
    *(ushort4*)(xc + (size_t)bl * DI + d0) = o;
}

// ---------------- Selective scan --------------------------------------------
__global__ __launch_bounds__(256) void scan_kernel(
    const float* __restrict__ xdbl,   // [B*L, 96] f32
    bf16* __restrict__ dty,           // [B*L, DI] dt in / y out
    const bf16* __restrict__ xc,      // [B*L, DI]  (u)
    const bf16* __restrict__ xz,      // [B*L, 2*DI] (z at +DI)
    const float* __restrict__ A_log,  // [DI, DS]
    const float* __restrict__ Dp)     // [DI]
{
    const int TC = 64;
    int b = blockIdx.x >> 7;
    int dblk = blockIdx.x & 127;
    int d0 = dblk * 16;
    int tid = threadIdx.x;
    int s = tid & 15;
    int dg = tid >> 4;
    int d = d0 + dg;
    float Ads = -__expf(A_log[(size_t)d * DS + s]);
    float h = 0.f;
    __shared__ float sdt[TC][16], su[TC][16], sB[TC][16], sC[TC][16], sy[TC][16];
    const size_t rowbase = (size_t)b * LL;
    int wi = tid >> 2;
    int wj = (tid & 3) * 4;
    float4 dpv = *(const float4*)(Dp + d0 + wj);

    for (int t0 = 0; t0 < LL; t0 += TC) {
        {
            size_t g = (rowbase + t0 + wi) * (size_t)DI + d0 + wj;
            *(float4*)&sdt[wi][wj] = ld4(dty + g);
            *(float4*)&su[wi][wj]  = ld4(xc + g);
        }
        #pragma unroll
        for (int r = 0; r < 4; r++) {
            int i = (tid >> 4) + r * 16;
            size_t g = (rowbase + t0 + i) * 96;
            sB[i][s] = xdbl[g + DTR + s];
            sC[i][s] = xdbl[g + DTR + DS + s];
        }
        __syncthreads();
        for (int i = 0; i < TC; i++) {
            float dtv = sdt[i][dg];
            float uv  = su[i][dg];
            float bv  = sB[i][s];
            float cv  = sC[i][s];
            float dA = __expf(dtv * Ads);
            h = dA * h + dtv * uv * bv;
            float yp = h * cv;
            yp += __shfl_xor(yp, 1);
            yp += __shfl_xor(yp, 2);
            yp += __shfl_xor(yp, 4);
            yp += __shfl_xor(yp, 8);
            if (s == 0) sy[i][dg] = yp;
        }
        __syncthreads();
        {
            size_t g  = (rowbase + t0 + wi) * (size_t)DI + d0 + wj;
            size_t gz = (rowbase + t0 + wi) * (size_t)(2 * DI) + DI + d0 + wj;
            float4 zv = ld4(xz + gz);
            float4 yv = *(const float4*)&sy[wi][wj];
            float4 uv = *(const float4*)&su[wi][wj];
            ushort4 o;
            o.x = f2b((yv.x + uv.x * dpv.x) * (zv.x / (1.f + __expf(-zv.x))));
            o.y = f2b((yv.y + uv.y * dpv.y) * (zv.y / (1.f + __expf(-zv.y))));
            o.z = f2b((yv.z + uv.z * dpv.z) * (zv.z / (1.f + __expf(-zv.z))));
            o.w = f2b((yv.w + uv.w * dpv.w) * (zv.w / (1.f + __expf(-zv.w))));
            *(ushort4*)(dty + g) = o;
        }
        __syncthreads();
    }
}

// ---------------------------------------------------------------------------
extern "C" void kernel_launch(void* const* d_in, const int* in_sizes, int n_in,
                              void* d_out, int out_size, void* d_ws, size_t ws_size,
                              hipStream_t stream)
{
    const float* x      = (const float*)d_in[0];
    const float* ln_w   = (const float*)d_in[1];
    const float* ln_b   = (const float*)d_in[2];
    const float* W_in   = (const float*)d_in[3];
    const float* conv_w = (const float*)d_in[4];
    const float* conv_b = (const float*)d_in[5];
    const float* W_x    = (const float*)d_in[6];
    const float* W_dt   = (const float*)d_in[7];
    const float* b_dt   = (const float*)d_in[8];
    const float* A_log  = (const float*)d_in[9];
    const float* Dp     = (const float*)d_in[10];
    const float* W_out  = (const float*)d_in[11];
    float* out = (float*)d_out;

    const size_t R = (size_t)BB * LL;   // 8192 rows

    // ws (~99 MB): xz bf16 64MB | dty bf16 32MB | xdbl f32 3MB
    bf16*  xz    = (bf16*)d_ws;                    // R * 2*DI
    bf16*  dty   = xz + R * 2 * DI;                // R * DI
    float* xdbl  = (float*)(dty + R * DI);         // R * 96
    // weight bf16 copies live in dead phases of existing regions:
    bf16*  W_in_b  = dty;   // 8MB inside dty; dead before dt-gemm writes dty
    bf16*  W_out_b = xz;    // 4MB inside xz; converted AFTER scan consumed z

    // d_out doubles as scratch: xn bf16 (phases 1-2), then xc bf16 (3-5),
    // then final f32 out (phase 6). All lifetimes strictly sequential.
    bf16* xn = (bf16*)d_out;            // R*DM bf16 (16.8 MB)
    bf16* xc = (bf16*)d_out;            // R*DI bf16 (33.5 MB)

    // 0. weight convert (W_in)
    f2b_kernel<<<(2 * DI * DM / 4) / 256, 256, 0, stream>>>(W_in, W_in_b, 2 * DI * DM / 4);

    // 1. LayerNorm -> xn bf16
    ln_kernel<<<(int)R, 256, 0, stream>>>(x, ln_w, ln_b, xn);

    // 2. in_proj (MFMA): xz[8192,4096] = xn @ W_in^T
    gemm_mfma<0, bf16><<<dim3(2 * DI / 128, R / 128), 256, 0, stream>>>(
        xn, DM, W_in_b, DM, xz, 2 * DI, DM, nullptr);

    // 3. conv + SiLU -> xc (overwrites xn; xn dead)
    conv_silu_kernel<<<(int)(R * DI / 4 / 256), 256, 0, stream>>>(
        xz, conv_w, conv_b, xc);

    // 4a. x_proj: xdbl[8192,96] = xc @ W_x^T   (f32)
    gemm_nt<0><<<dim3(2, R / 64), 256, 0, stream>>>(
        xc, DI, W_x, DI, xdbl, 96, (int)R, 96, DI, nullptr);

    // 4b. dt = softplus(xdbl[:,:64] @ W_dt^T + b_dt) -> dty bf16 (kills W_in_b)
    gemm_nt<1><<<dim3(DI / 64, R / 64), 256, 0, stream>>>(
        xdbl, 96, W_dt, DTR, dty, DI, (int)R, DI, DTR, b_dt);

    // 5. selective scan + D-skip + z-gate (y overwrites dty)
    scan_kernel<<<BB * (DI / 16), 256, 0, stream>>>(
        xdbl, dty, xc, xz, A_log, Dp);

    // 5b. weight convert (W_out) into xz head (z now dead)
    f2b_kernel<<<(DM * DI / 4) / 256, 256, 0, stream>>>(W_out, W_out_b, DM * DI / 4);

    // 6. out_proj (MFMA) + residual: out = y @ W_out^T + x
    gemm_mfma<2, float><<<dim3(DM / 128, R / 128), 256, 0, stream>>>(
        dty, DI, W_out_b, DI, out, DM, DI, x);
}

// Round 4
// 925.389 us; speedup vs baseline: 2.5005x; 1.1631x over previous
//
#include <hip/hip_runtime.h>
#include <math.h>

#define BB 4
#define LL 2048
#define DM 1024
#define DI 2048
#define DS 16
#define DTR 64
#define NC 16            // scan chunks per sequence
#define CHUNK (LL / NC)  // 128

typedef unsigned short bf16;
typedef __attribute__((ext_vector_type(8))) short bf16x8;
typedef __attribute__((ext_vector_type(4))) float f32x4;

__device__ inline float b2f(bf16 u) { return __uint_as_float(((unsigned)u) << 16); }
__device__ inline bf16 f2b(float f) {
    unsigned u = __float_as_uint(f);
    u += 0x7FFF + ((u >> 16) & 1);   // round-to-nearest-even
    return (bf16)(u >> 16);
}

__device__ inline float4 ld4(const float* p) { return *(const float4*)p; }
__device__ inline float4 ld4(const bf16* p) {
    ushort4 v = *(const ushort4*)p;
    return make_float4(b2f(v.x), b2f(v.y), b2f(v.z), b2f(v.w));
}
__device__ inline void st1(float* p, float v) { *p = v; }
__device__ inline void st1(bf16* p, float v) { *p = f2b(v); }

// async global->LDS, 16 bytes per lane; LDS dest = wave-uniform base + lane*16
__device__ inline void gld_lds16(const void* g, void* l) {
    __builtin_amdgcn_global_load_lds(
        (const __attribute__((address_space(1))) unsigned int*)g,
        (__attribute__((address_space(3))) unsigned int*)l, 16, 0, 0);
}

// ---------------- f32 -> bf16 convert (weights) ------------------------------
__global__ __launch_bounds__(256) void f2b_kernel(const float* __restrict__ in,
    bf16* __restrict__ out, int n4)
{
    int i = blockIdx.x * 256 + threadIdx.x;
    if (i >= n4) return;
    float4 v = *(const float4*)(in + (size_t)i * 4);
    ushort4 o = { f2b(v.x), f2b(v.y), f2b(v.z), f2b(v.w) };
    *(ushort4*)(out + (size_t)i * 4) = o;
}

// ---------------- LayerNorm: one block per row, bf16 out ---------------------
__global__ __launch_bounds__(256) void ln_kernel(const float* __restrict__ x,
    const float* __restrict__ w, const float* __restrict__ b,
    bf16* __restrict__ xn)
{
    int row = blockIdx.x;
    int tid = threadIdx.x;
    const float* xr = x + (size_t)row * DM;
    float4 v = *(const float4*)(xr + tid * 4);
    float s1 = v.x + v.y + v.z + v.w;
    float s2 = v.x * v.x + v.y * v.y + v.z * v.z + v.w * v.w;
    #pragma unroll
    for (int o = 32; o > 0; o >>= 1) {
        s1 += __shfl_xor(s1, o);
        s2 += __shfl_xor(s2, o);
    }
    __shared__ float r1[4], r2[4];
    __shared__ float smu, srs;
    int wv = tid >> 6;
    if ((tid & 63) == 0) { r1[wv] = s1; r2[wv] = s2; }
    __syncthreads();
    if (tid == 0) {
        float t1 = r1[0] + r1[1] + r1[2] + r1[3];
        float t2 = r2[0] + r2[1] + r2[2] + r2[3];
        float mu = t1 * (1.0f / DM);
        float var = t2 * (1.0f / DM) - mu * mu;
        smu = mu;
        srs = rsqrtf(var + 1e-5f);
    }
    __syncthreads();
    float mu = smu, rs = srs;
    float4 wv4 = *(const float4*)(w + tid * 4);
    float4 bv4 = *(const float4*)(b + tid * 4);
    ushort4 o;
    o.x = f2b((v.x - mu) * rs * wv4.x + bv4.x);
    o.y = f2b((v.y - mu) * rs * wv4.y + bv4.y);
    o.z = f2b((v.z - mu) * rs * wv4.z + bv4.z);
    o.w = f2b((v.w - mu) * rs * wv4.w + bv4.w);
    *(ushort4*)(xn + (size_t)row * DM + tid * 4) = o;
}

// ---------------- MFMA bf16 GEMM, NT: C[m,n] = sum_k A[m,k]*B[n,k] ----------
template<int EPI, typename TC>
__global__ __launch_bounds__(256) void gemm_mfma(
    const bf16* __restrict__ A, int lda,
    const bf16* __restrict__ B, int ldb,
    TC* __restrict__ C, int ldc,
    int K, const float* __restrict__ aux)
{
    __shared__ bf16 As[128 * 32];
    __shared__ bf16 Bs[128 * 32];
    const int tid = threadIdx.x;
    const int lane = tid & 63;
    const int w = tid >> 6;
    const int wm = w >> 1, wn = w & 1;
    const int m0 = blockIdx.y * 128, n0 = blockIdx.x * 128;

    const int srow = lane >> 2;
    const int schunk = (lane & 3) * 8;

    const int fm = lane & 15;
    const int fq = lane >> 4;

    f32x4 acc[4][4] = {};

    for (int kt = 0; kt < K; kt += 32) {
        #pragma unroll
        for (int i = 0; i < 2; i++) {
            int r0 = i * 64 + w * 16;
            gld_lds16(A + (size_t)(m0 + r0 + srow) * lda + kt + schunk, &As[r0 * 32]);
            gld_lds16(B + (size_t)(n0 + r0 + srow) * ldb + kt + schunk, &Bs[r0 * 32]);
        }
        __syncthreads();
        bf16x8 af[4], bfr[4];
        #pragma unroll
        for (int i = 0; i < 4; i++) {
            af[i]  = *(const bf16x8*)&As[(wm * 64 + i * 16 + fm) * 32 + fq * 8];
            bfr[i] = *(const bf16x8*)&Bs[(wn * 64 + i * 16 + fm) * 32 + fq * 8];
        }
        #pragma unroll
        for (int i = 0; i < 4; i++)
            #pragma unroll
            for (int j = 0; j < 4; j++)
                acc[i][j] = __builtin_amdgcn_mfma_f32_16x16x32_bf16(
                    af[i], bfr[j], acc[i][j], 0, 0, 0);
        __syncthreads();
    }

    #pragma unroll
    for (int i = 0; i < 4; i++) {
        #pragma unroll
        for (int r = 0; r < 4; r++) {
            int m = m0 + wm * 64 + i * 16 + fq * 4 + r;
            #pragma unroll
            for (int j = 0; j < 4; j++) {
                int n = n0 + wn * 64 + j * 16 + fm;
                float v = acc[i][j][r];
                if (EPI == 2) v += aux[(size_t)m * ldc + n];
                st1(&C[(size_t)m * ldc + n], v);
            }
        }
    }
}

// ---------------- Tiled f32-compute GEMM (small shapes), NT ------------------
template<int EPI, typename TA, typename TB, typename TC>
__global__ __launch_bounds__(256) void gemm_nt(
    const TA* __restrict__ A, int lda,
    const TB* __restrict__ B, int ldb,
    TC* __restrict__ C, int ldc,
    int M, int N, int K,
    const float* __restrict__ aux)
{
    __shared__ float As[16][64];
    __shared__ float Bs[16][64];
    int tid = threadIdx.x;
    int m0 = blockIdx.y * 64, n0 = blockIdx.x * 64;
    int lr = tid >> 2;
    int lc = (tid & 3) * 4;
    int tm = tid >> 4;
    int tn = tid & 15;
    float acc[4][4] = {};
    for (int kt = 0; kt < K; kt += 16) {
        float4 av = ld4(A + (size_t)(m0 + lr) * lda + kt + lc);
        float4 bv = make_float4(0.f, 0.f, 0.f, 0.f);
        if (n0 + lr < N)
            bv = ld4(B + (size_t)(n0 + lr) * ldb + kt + lc);
        As[lc + 0][lr] = av.x; As[lc + 1][lr] = av.y;
        As[lc + 2][lr] = av.z; As[lc + 3][lr] = av.w;
        Bs[lc + 0][lr] = bv.x; Bs[lc + 1][lr] = bv.y;
        Bs[lc + 2][lr] = bv.z; Bs[lc + 3][lr] = bv.w;
        __syncthreads();
        #pragma unroll
        for (int k = 0; k < 16; k++) {
            float4 a4 = *(const float4*)&As[k][tm * 4];
            float4 b4 = *(const float4*)&Bs[k][tn * 4];
            float am[4] = {a4.x, a4.y, a4.z, a4.w};
            float bn[4] = {b4.x, b4.y, b4.z, b4.w};
            #pragma unroll
            for (int i = 0; i < 4; i++)
                #pragma unroll
                for (int j = 0; j < 4; j++)
                    acc[i][j] = fmaf(am[i], bn[j], acc[i][j]);
        }
        __syncthreads();
    }
    #pragma unroll
    for (int i = 0; i < 4; i++) {
        int m = m0 + tm * 4 + i;
        #pragma unroll
        for (int j = 0; j < 4; j++) {
            int n = n0 + tn * 4 + j;
            if (n >= N) continue;
            float v = acc[i][j];
            if (EPI == 1) {
                v += aux[n];
                v = (v > 20.f) ? v : log1pf(__expf(v));
            }
            st1(&C[(size_t)m * ldc + n], v);
        }
    }
}

// ---------------- Depthwise causal conv (4 taps) + SiLU ----------------------
__global__ __launch_bounds__(256) void conv_silu_kernel(
    const bf16* __restrict__ xz, const float* __restrict__ cw,
    const float* __restrict__ cb, bf16* __restrict__ xc)
{
    int idx = blockIdx.x * 256 + threadIdx.x;
    int d4 = idx & (DI / 4 - 1);
    int bl = idx >> 9;
    int l = bl & (LL - 1);
    int d0 = d4 * 4;
    float4 bias = *(const float4*)(cb + d0);
    float acc[4] = {bias.x, bias.y, bias.z, bias.w};
    #pragma unroll
    for (int k = 0; k < 4; k++) {
        int lp = l - 3 + k;
        if (lp < 0) continue;
        float4 xv = ld4(xz + (size_t)(bl - 3 + k) * (2 * DI) + d0);
        acc[0] = fmaf(xv.x, cw[(d0 + 0) * 4 + k], acc[0]);
        acc[1] = fmaf(xv.y, cw[(d0 + 1) * 4 + k], acc[1]);
        acc[2] = fmaf(xv.z, cw[(d0 + 2) * 4 + k], acc[2]);
        acc[3] = fmaf(xv.w, cw[(d0 + 3) * 4 + k], acc[3]);
    }
    ushort4 o;
    o.x = f2b(acc[0] / (1.f + __expf(-acc[0])));
    o.y = f2b(acc[1] / (1.f + __expf(-acc[1])));
    o.z = f2b(acc[2] / (1.f + __expf(-acc[2])));
    o.w = f2b(acc[3] / (1.f + __expf(-acc[3])));
    *(ushort4*)(xc + (size_t)bl * DI + d0) = o;
}

// ---------------- Chunked selective scan -------------------------------------
// Phase 1: per (b, chunk, 16 channels): P = prod(dA), S = local end state.
__global__ __launch_bounds__(256) void scan_part1(
    const float* __restrict__ xdbl, const bf16* __restrict__ dty,
    const bf16* __restrict__ xc, const float* __restrict__ A_log,
    float* __restrict__ P, float* __restrict__ S)
{
    const int TC = 64;
    int bid = blockIdx.x;
    int dblk = bid & 127;
    int c = (bid >> 7) & (NC - 1);
    int b = bid >> 11;
    int d0 = dblk * 16;
    int tid = threadIdx.x;
    int s = tid & 15;
    int dg = tid >> 4;
    int d = d0 + dg;
    float Ads = -__expf(A_log[(size_t)d * DS + s]);
    float h = 0.f, p = 1.f;
    __shared__ float sdt[TC][16], su[TC][16], sB[TC][16];
    const size_t rowbase = (size_t)b * LL + c * CHUNK;
    int wi = tid >> 2;
    int wj = (tid & 3) * 4;
    for (int t0 = 0; t0 < CHUNK; t0 += TC) {
        {
            size_t g = (rowbase + t0 + wi) * (size_t)DI + d0 + wj;
            *(float4*)&sdt[wi][wj] = ld4(dty + g);
            *(float4*)&su[wi][wj]  = ld4(xc + g);
        }
        #pragma unroll
        for (int r = 0; r < 4; r++) {
            int i = (tid >> 4) + r * 16;
            sB[i][s] = xdbl[(rowbase + t0 + i) * 96 + DTR + s];
        }
        __syncthreads();
        for (int i = 0; i < TC; i++) {
            float dtv = sdt[i][dg];
            float dA = __expf(dtv * Ads);
            h = dA * h + dtv * su[i][dg] * sB[i][s];
            p *= dA;
        }
        __syncthreads();
    }
    size_t o = ((size_t)(b * NC + c) * DI + d) * DS + s;
    P[o] = p;
    S[o] = h;
}

// Phase 2: fold chunk summaries; writes entry state h_in in-place over S.
__global__ __launch_bounds__(256) void scan_combine(
    const float* __restrict__ P, float* __restrict__ S)
{
    int g = blockIdx.x * 256 + threadIdx.x;   // B*DI*DS threads
    int b = g >> 15;                          // DI*DS = 32768
    int rem = g & 32767;
    float h = 0.f;
    #pragma unroll
    for (int c = 0; c < NC; c++) {
        size_t o = ((size_t)(b * NC + c) << 15) + rem;
        float p = P[o], sv = S[o];
        S[o] = h;                             // h_in for chunk c
        h = p * h + sv;
    }
}

// Phase 3: full scan per chunk starting from h_in, with y + gate epilogue.
__global__ __launch_bounds__(256) void scan_part2(
    const float* __restrict__ xdbl, bf16* __restrict__ dty,
    const bf16* __restrict__ xc, const bf16* __restrict__ xz,
    const float* __restrict__ A_log, const float* __restrict__ Dp,
    const float* __restrict__ Hin)
{
    const int TC = 64;
    int bid = blockIdx.x;
    int dblk = bid & 127;
    int c = (bid >> 7) & (NC - 1);
    int b = bid >> 11;
    int d0 = dblk * 16;
    int tid = threadIdx.x;
    int s = tid & 15;
    int dg = tid >> 4;
    int d = d0 + dg;
    float Ads = -__expf(A_log[(size_t)d * DS + s]);
    float h = Hin[((size_t)(b * NC + c) * DI + d) * DS + s];
    __shared__ float sdt[TC][16], su[TC][16], sB[TC][16], sC[TC][16], sy[TC][16];
    const size_t rowbase = (size_t)b * LL + c * CHUNK;
    int wi = tid >> 2;
    int wj = (tid & 3) * 4;
    float4 dpv = *(const float4*)(Dp + d0 + wj);

    for (int t0 = 0; t0 < CHUNK; t0 += TC) {
        {
            size_t g = (rowbase + t0 + wi) * (size_t)DI + d0 + wj;
            *(float4*)&sdt[wi][wj] = ld4(dty + g);
            *(float4*)&su[wi][wj]  = ld4(xc + g);
        }
        #pragma unroll
        for (int r = 0; r < 4; r++) {
            int i = (tid >> 4) + r * 16;
            size_t g = (rowbase + t0 + i) * 96;
            sB[i][s] = xdbl[g + DTR + s];
            sC[i][s] = xdbl[g + DTR + DS + s];
        }
        __syncthreads();
        for (int i = 0; i < TC; i++) {
            float dtv = sdt[i][dg];
            float dA = __expf(dtv * Ads);
            h = dA * h + dtv * su[i][dg] * sB[i][s];
            float yp = h * sC[i][s];
            yp += __shfl_xor(yp, 1);
            yp += __shfl_xor(yp, 2);
            yp += __shfl_xor(yp, 4);
            yp += __shfl_xor(yp, 8);
            if (s == 0) sy[i][dg] = yp;
        }
        __syncthreads();
        {
            size_t g  = (rowbase + t0 + wi) * (size_t)DI + d0 + wj;
            size_t gz = (rowbase + t0 + wi) * (size_t)(2 * DI) + DI + d0 + wj;
            float4 zv = ld4(xz + gz);
            float4 yv = *(const float4*)&sy[wi][wj];
            float4 uv = *(const float4*)&su[wi][wj];
            ushort4 o;
            o.x = f2b((yv.x + uv.x * dpv.x) * (zv.x / (1.f + __expf(-zv.x))));
            o.y = f2b((yv.y + uv.y * dpv.y) * (zv.y / (1.f + __expf(-zv.y))));
            o.z = f2b((yv.z + uv.z * dpv.z) * (zv.z / (1.f + __expf(-zv.z))));
            o.w = f2b((yv.w + uv.w * dpv.w) * (zv.w / (1.f + __expf(-zv.w))));
            *(ushort4*)(dty + g) = o;
        }
        __syncthreads();
    }
}

// ---------------- Monolithic scan (fallback when ws is small) ----------------
__global__ __launch_bounds__(256) void scan_mono(
    const float* __restrict__ xdbl, bf16* __restrict__ dty,
    const bf16* __restrict__ xc, const bf16* __restrict__ xz,
    const float* __restrict__ A_log, const float* __restrict__ Dp)
{
    const int TC = 64;
    int b = blockIdx.x >> 7;
    int dblk = blockIdx.x & 127;
    int d0 = dblk * 16;
    int tid = threadIdx.x;
    int s = tid & 15;
    int dg = tid >> 4;
    int d = d0 + dg;
    float Ads = -__expf(A_log[(size_t)d * DS + s]);
    float h = 0.f;
    __shared__ float sdt[TC][16], su[TC][16], sB[TC][16], sC[TC][16], sy[TC][16];
    const size_t rowbase = (size_t)b * LL;
    int wi = tid >> 2;
    int wj = (tid & 3) * 4;
    float4 dpv = *(const float4*)(Dp + d0 + wj);
    for (int t0 = 0; t0 < LL; t0 += TC) {
        {
            size_t g = (rowbase + t0 + wi) * (size_t)DI + d0 + wj;
            *(float4*)&sdt[wi][wj] = ld4(dty + g);
            *(float4*)&su[wi][wj]  = ld4(xc + g);
        }
        #pragma unroll
        for (int r = 0; r < 4; r++) {
            int i = (tid >> 4) + r * 16;
            size_t g = (rowbase + t0 + i) * 96;
            sB[i][s] = xdbl[g + DTR + s];
            sC[i][s] = xdbl[g + DTR + DS + s];
        }
        __syncthreads();
        for (int i = 0; i < TC; i++) {
            float dtv = sdt[i][dg];
            float dA = __expf(dtv * Ads);
            h = dA * h + dtv * su[i][dg] * sB[i][s];
            float yp = h * sC[i][s];
            yp += __shfl_xor(yp, 1);
            yp += __shfl_xor(yp, 2);
            yp += __shfl_xor(yp, 4);
            yp += __shfl_xor(yp, 8);
            if (s == 0) sy[i][dg] = yp;
        }
        __syncthreads();
        {
            size_t g  = (rowbase + t0 + wi) * (size_t)DI + d0 + wj;
            size_t gz = (rowbase + t0 + wi) * (size_t)(2 * DI) + DI + d0 + wj;
            float4 zv = ld4(xz + gz);
            float4 yv = *(const float4*)&sy[wi][wj];
            float4 uv = *(const float4*)&su[wi][wj];
            ushort4 o;
            o.x = f2b((yv.x + uv.x * dpv.x) * (zv.x / (1.f + __expf(-zv.x))));
            o.y = f2b((yv.y + uv.y * dpv.y) * (zv.y / (1.f + __expf(-zv.y))));
            o.z = f2b((yv.z + uv.z * dpv.z) * (zv.z / (1.f + __expf(-zv.z))));
            o.w = f2b((yv.w + uv.w * dpv.w) * (zv.w / (1.f + __expf(-zv.w))));
            *(ushort4*)(dty + g) = o;
        }
        __syncthreads();
    }
}

// ---------------------------------------------------------------------------
extern "C" void kernel_launch(void* const* d_in, const int* in_sizes, int n_in,
                              void* d_out, int out_size, void* d_ws, size_t ws_size,
                              hipStream_t stream)
{
    const float* x      = (const float*)d_in[0];
    const float* ln_w   = (const float*)d_in[1];
    const float* ln_b   = (const float*)d_in[2];
    const float* W_in   = (const float*)d_in[3];
    const float* conv_w = (const float*)d_in[4];
    const float* conv_b = (const float*)d_in[5];
    const float* W_x    = (const float*)d_in[6];
    const float* W_dt   = (const float*)d_in[7];
    const float* b_dt   = (const float*)d_in[8];
    const float* A_log  = (const float*)d_in[9];
    const float* Dp     = (const float*)d_in[10];
    const float* W_out  = (const float*)d_in[11];
    float* out = (float*)d_out;

    const size_t R = (size_t)BB * LL;   // 8192 rows

    // ws: xz bf16 64MB | dty bf16 32MB | xdbl f32 3MB | P,S f32 8MB each
    bf16*  xz    = (bf16*)d_ws;                    // R * 2*DI
    bf16*  dty   = xz + R * 2 * DI;                // R * DI
    float* xdbl  = (float*)(dty + R * DI);         // R * 96
    float* Pbuf  = xdbl + R * 96;                  // B*NC*DI*DS
    float* Sbuf  = Pbuf + (size_t)BB * NC * DI * DS;
    const size_t ws_need = (size_t)((char*)(Sbuf + (size_t)BB * NC * DI * DS) - (char*)d_ws);
    const bool chunked = ws_size >= ws_need;

    bf16*  W_in_b  = dty;   // dead before dt-gemm writes dty
    bf16*  W_out_b = xz;    // converted AFTER scan consumed z

    bf16* xn = (bf16*)d_out;
    bf16* xc = (bf16*)d_out;

    // 0. weight convert (W_in)
    f2b_kernel<<<(2 * DI * DM / 4) / 256, 256, 0, stream>>>(W_in, W_in_b, 2 * DI * DM / 4);

    // 1. LayerNorm -> xn bf16
    ln_kernel<<<(int)R, 256, 0, stream>>>(x, ln_w, ln_b, xn);

    // 2. in_proj (MFMA): xz[8192,4096] = xn @ W_in^T
    gemm_mfma<0, bf16><<<dim3(2 * DI / 128, R / 128), 256, 0, stream>>>(
        xn, DM, W_in_b, DM, xz, 2 * DI, DM, nullptr);

    // 3. conv + SiLU -> xc
    conv_silu_kernel<<<(int)(R * DI / 4 / 256), 256, 0, stream>>>(
        xz, conv_w, conv_b, xc);

    // 4a. x_proj: xdbl[8192,96] = xc @ W_x^T   (f32)
    gemm_nt<0><<<dim3(2, R / 64), 256, 0, stream>>>(
        xc, DI, W_x, DI, xdbl, 96, (int)R, 96, DI, nullptr);

    // 4b. dt = softplus(xdbl[:,:64] @ W_dt^T + b_dt) -> dty bf16
    gemm_nt<1><<<dim3(DI / 64, R / 64), 256, 0, stream>>>(
        xdbl, 96, W_dt, DTR, dty, DI, (int)R, DI, DTR, b_dt);

    // 5. selective scan + D-skip + z-gate (y overwrites dty)
    if (chunked) {
        scan_part1<<<BB * NC * (DI / 16), 256, 0, stream>>>(
            xdbl, dty, xc, A_log, Pbuf, Sbuf);
        scan_combine<<<BB * DI * DS / 256, 256, 0, stream>>>(Pbuf, Sbuf);
        scan_part2<<<BB * NC * (DI / 16), 256, 0, stream>>>(
            xdbl, dty, xc, xz, A_log, Dp, Sbuf);
    } else {
        scan_mono<<<BB * (DI / 16), 256, 0, stream>>>(
            xdbl, dty, xc, xz, A_log, Dp);
    }

    // 5b. weight convert (W_out) into xz head (z now dead)
    f2b_kernel<<<(DM * DI / 4) / 256, 256, 0, stream>>>(W_out, W_out_b, DM * DI / 4);

    // 6. out_proj (MFMA) + residual: out = y @ W_out^T + x
    gemm_mfma<2, float><<<dim3(DM / 128, R / 128), 256, 0, stream>>>(
        dty, DI, W_out_b, DI, out, DM, DI, x);
}

// Round 5
// 744.148 us; speedup vs baseline: 3.1095x; 1.2436x over previous
//
#include <hip/hip_runtime.h>
#include <math.h>

#define BB 4
#define LL 2048
#define DM 1024
#define DI 2048
#define DS 16
#define DTR 64
#define NC 16            // scan chunks per sequence
#define CHUNK (LL / NC)  // 128
#define TCH 256          // channels per scan block
#define TT 32            // timesteps per staged tile

typedef unsigned short bf16;
typedef __attribute__((ext_vector_type(8))) short bf16x8;
typedef __attribute__((ext_vector_type(4))) float f32x4;

__device__ inline float b2f(bf16 u) { return __uint_as_float(((unsigned)u) << 16); }
__device__ inline bf16 f2b(float f) {
    unsigned u = __float_as_uint(f);
    u += 0x7FFF + ((u >> 16) & 1);   // round-to-nearest-even
    return (bf16)(u >> 16);
}

__device__ inline float4 ld4(const float* p) { return *(const float4*)p; }
__device__ inline float4 ld4(const bf16* p) {
    ushort4 v = *(const ushort4*)p;
    return make_float4(b2f(v.x), b2f(v.y), b2f(v.z), b2f(v.w));
}
__device__ inline void st1(float* p, float v) { *p = v; }
__device__ inline void st1(bf16* p, float v) { *p = f2b(v); }

// async global->LDS, 16 bytes per lane; LDS dest = wave-uniform base + lane*16
__device__ inline void gld_lds16(const void* g, void* l) {
    __builtin_amdgcn_global_load_lds(
        (const __attribute__((address_space(1))) unsigned int*)g,
        (__attribute__((address_space(3))) unsigned int*)l, 16, 0, 0);
}

// ---------------- f32 -> bf16 convert (weights) ------------------------------
__global__ __launch_bounds__(256) void f2b_kernel(const float* __restrict__ in,
    bf16* __restrict__ out, int n4)
{
    int i = blockIdx.x * 256 + threadIdx.x;
    if (i >= n4) return;
    float4 v = *(const float4*)(in + (size_t)i * 4);
    ushort4 o = { f2b(v.x), f2b(v.y), f2b(v.z), f2b(v.w) };
    *(ushort4*)(out + (size_t)i * 4) = o;
}

// ---------------- LayerNorm: one block per row, bf16 out ---------------------
__global__ __launch_bounds__(256) void ln_kernel(const float* __restrict__ x,
    const float* __restrict__ w, const float* __restrict__ b,
    bf16* __restrict__ xn)
{
    int row = blockIdx.x;
    int tid = threadIdx.x;
    const float* xr = x + (size_t)row * DM;
    float4 v = *(const float4*)(xr + tid * 4);
    float s1 = v.x + v.y + v.z + v.w;
    float s2 = v.x * v.x + v.y * v.y + v.z * v.z + v.w * v.w;
    #pragma unroll
    for (int o = 32; o > 0; o >>= 1) {
        s1 += __shfl_xor(s1, o);
        s2 += __shfl_xor(s2, o);
    }
    __shared__ float r1[4], r2[4];
    __shared__ float smu, srs;
    int wv = tid >> 6;
    if ((tid & 63) == 0) { r1[wv] = s1; r2[wv] = s2; }
    __syncthreads();
    if (tid == 0) {
        float t1 = r1[0] + r1[1] + r1[2] + r1[3];
        float t2 = r2[0] + r2[1] + r2[2] + r2[3];
        float mu = t1 * (1.0f / DM);
        float var = t2 * (1.0f / DM) - mu * mu;
        smu = mu;
        srs = rsqrtf(var + 1e-5f);
    }
    __syncthreads();
    float mu = smu, rs = srs;
    float4 wv4 = *(const float4*)(w + tid * 4);
    float4 bv4 = *(const float4*)(b + tid * 4);
    ushort4 o;
    o.x = f2b((v.x - mu) * rs * wv4.x + bv4.x);
    o.y = f2b((v.y - mu) * rs * wv4.y + bv4.y);
    o.z = f2b((v.z - mu) * rs * wv4.z + bv4.z);
    o.w = f2b((v.w - mu) * rs * wv4.w + bv4.w);
    *(ushort4*)(xn + (size_t)row * DM + tid * 4) = o;
}

// ---------------- MFMA bf16 GEMM, NT: C[m,n] = sum_k A[m,k]*B[n,k] ----------
template<int EPI, typename TC>
__global__ __launch_bounds__(256) void gemm_mfma(
    const bf16* __restrict__ A, int lda,
    const bf16* __restrict__ B, int ldb,
    TC* __restrict__ C, int ldc,
    int K, const float* __restrict__ aux)
{
    __shared__ bf16 As[128 * 32];
    __shared__ bf16 Bs[128 * 32];
    const int tid = threadIdx.x;
    const int lane = tid & 63;
    const int w = tid >> 6;
    const int wm = w >> 1, wn = w & 1;
    const int m0 = blockIdx.y * 128, n0 = blockIdx.x * 128;

    const int srow = lane >> 2;
    const int schunk = (lane & 3) * 8;

    const int fm = lane & 15;
    const int fq = lane >> 4;

    f32x4 acc[4][4] = {};

    for (int kt = 0; kt < K; kt += 32) {
        #pragma unroll
        for (int i = 0; i < 2; i++) {
            int r0 = i * 64 + w * 16;
            gld_lds16(A + (size_t)(m0 + r0 + srow) * lda + kt + schunk, &As[r0 * 32]);
            gld_lds16(B + (size_t)(n0 + r0 + srow) * ldb + kt + schunk, &Bs[r0 * 32]);
        }
        __syncthreads();
        bf16x8 af[4], bfr[4];
        #pragma unroll
        for (int i = 0; i < 4; i++) {
            af[i]  = *(const bf16x8*)&As[(wm * 64 + i * 16 + fm) * 32 + fq * 8];
            bfr[i] = *(const bf16x8*)&Bs[(wn * 64 + i * 16 + fm) * 32 + fq * 8];
        }
        #pragma unroll
        for (int i = 0; i < 4; i++)
            #pragma unroll
            for (int j = 0; j < 4; j++)
                acc[i][j] = __builtin_amdgcn_mfma_f32_16x16x32_bf16(
                    af[i], bfr[j], acc[i][j], 0, 0, 0);
        __syncthreads();
    }

    #pragma unroll
    for (int i = 0; i < 4; i++) {
        #pragma unroll
        for (int r = 0; r < 4; r++) {
            int m = m0 + wm * 64 + i * 16 + fq * 4 + r;
            #pragma unroll
            for (int j = 0; j < 4; j++) {
                int n = n0 + wn * 64 + j * 16 + fm;
                float v = acc[i][j][r];
                if (EPI == 2) v += aux[(size_t)m * ldc + n];
                st1(&C[(size_t)m * ldc + n], v);
            }
        }
    }
}

// ---------------- Tiled f32-compute GEMM (small shapes), NT ------------------
template<int EPI, typename TA, typename TB, typename TC>
__global__ __launch_bounds__(256) void gemm_nt(
    const TA* __restrict__ A, int lda,
    const TB* __restrict__ B, int ldb,
    TC* __restrict__ C, int ldc,
    int M, int N, int K,
    const float* __restrict__ aux)
{
    __shared__ float As[16][64];
    __shared__ float Bs[16][64];
    int tid = threadIdx.x;
    int m0 = blockIdx.y * 64, n0 = blockIdx.x * 64;
    int lr = tid >> 2;
    int lc = (tid & 3) * 4;
    int tm = tid >> 4;
    int tn = tid & 15;
    float acc[4][4] = {};
    for (int kt = 0; kt < K; kt += 16) {
        float4 av = ld4(A + (size_t)(m0 + lr) * lda + kt + lc);
        float4 bv = make_float4(0.f, 0.f, 0.f, 0.f);
        if (n0 + lr < N)
            bv = ld4(B + (size_t)(n0 + lr) * ldb + kt + lc);
        As[lc + 0][lr] = av.x; As[lc + 1][lr] = av.y;
        As[lc + 2][lr] = av.z; As[lc + 3][lr] = av.w;
        Bs[lc + 0][lr] = bv.x; Bs[lc + 1][lr] = bv.y;
        Bs[lc + 2][lr] = bv.z; Bs[lc + 3][lr] = bv.w;
        __syncthreads();
        #pragma unroll
        for (int k = 0; k < 16; k++) {
            float4 a4 = *(const float4*)&As[k][tm * 4];
            float4 b4 = *(const float4*)&Bs[k][tn * 4];
            float am[4] = {a4.x, a4.y, a4.z, a4.w};
            float bn[4] = {b4.x, b4.y, b4.z, b4.w};
            #pragma unroll
            for (int i = 0; i < 4; i++)
                #pragma unroll
                for (int j = 0; j < 4; j++)
                    acc[i][j] = fmaf(am[i], bn[j], acc[i][j]);
        }
        __syncthreads();
    }
    #pragma unroll
    for (int i = 0; i < 4; i++) {
        int m = m0 + tm * 4 + i;
        #pragma unroll
        for (int j = 0; j < 4; j++) {
            int n = n0 + tn * 4 + j;
            if (n >= N) continue;
            float v = acc[i][j];
            if (EPI == 1) {
                v += aux[n];
                v = (v > 20.f) ? v : log1pf(__expf(v));
            }
            st1(&C[(size_t)m * ldc + n], v);
        }
    }
}

// ---------------- Depthwise causal conv (4 taps) + SiLU ----------------------
__global__ __launch_bounds__(256) void conv_silu_kernel(
    const bf16* __restrict__ xz, const float* __restrict__ cw,
    const float* __restrict__ cb, bf16* __restrict__ xc)
{
    int idx = blockIdx.x * 256 + threadIdx.x;
    int d4 = idx & (DI / 4 - 1);
    int bl = idx >> 9;
    int l = bl & (LL - 1);
    int d0 = d4 * 4;
    float4 bias = *(const float4*)(cb + d0);
    float acc[4] = {bias.x, bias.y, bias.z, bias.w};
    #pragma unroll
    for (int k = 0; k < 4; k++) {
        int lp = l - 3 + k;
        if (lp < 0) continue;
        float4 xv = ld4(xz + (size_t)(bl - 3 + k) * (2 * DI) + d0);
        acc[0] = fmaf(xv.x, cw[(d0 + 0) * 4 + k], acc[0]);
        acc[1] = fmaf(xv.y, cw[(d0 + 1) * 4 + k], acc[1]);
        acc[2] = fmaf(xv.z, cw[(d0 + 2) * 4 + k], acc[2]);
        acc[3] = fmaf(xv.w, cw[(d0 + 3) * 4 + k], acc[3]);
    }
    ushort4 o;
    o.x = f2b(acc[0] / (1.f + __expf(-acc[0])));
    o.y = f2b(acc[1] / (1.f + __expf(-acc[1])));
    o.z = f2b(acc[2] / (1.f + __expf(-acc[2])));
    o.w = f2b(acc[3] / (1.f + __expf(-acc[3])));
    *(ushort4*)(xc + (size_t)bl * DI + d0) = o;
}

// ---------------- Chunked selective scan, thread-per-channel -----------------
// Block: 256 threads = 256 channels; h[16] states per thread in registers.
// No cross-lane reduce. dt/u/z staged bf16 [TT][256]; B/C staged f32 [TT][32]
// from xdbl cols 64..95 (contiguous 128B/row) and read via broadcast b128.

// Phase 1: per (b, chunk, chgroup): P = prod(dA), S = local end state.
__global__ __launch_bounds__(256) void scan_part1(
    const float* __restrict__ xdbl, const bf16* __restrict__ dty,
    const bf16* __restrict__ xc, const float* __restrict__ A_log,
    float* __restrict__ P, float* __restrict__ S)
{
    __shared__ bf16 sdt[TT][TCH];
    __shared__ bf16 su[TT][TCH];
    __shared__ alignas(16) float sBC[TT][32];
    int bid = blockIdx.x;
    int cg = bid & 7;                 // DI/TCH = 8
    int c  = (bid >> 3) & (NC - 1);
    int b  = bid >> 7;
    int d0 = cg * TCH;
    int tid = threadIdx.x;
    int w = tid >> 6, l = tid & 63;
    int lrow = l >> 5, lcol = (l & 31) * 8;   // bf16 tensors: 2 rows/wave-op
    int brow = l >> 3, bcol = (l & 7) * 4;    // xdbl f32: 8 rows/wave-op
    int d = d0 + tid;

    float Ads[16];
    #pragma unroll
    for (int q = 0; q < 4; q++) {
        float4 a4 = *(const float4*)&A_log[(size_t)d * DS + q * 4];
        Ads[q*4+0] = -__expf(a4.x); Ads[q*4+1] = -__expf(a4.y);
        Ads[q*4+2] = -__expf(a4.z); Ads[q*4+3] = -__expf(a4.w);
    }
    float h[16], p[16];
    #pragma unroll
    for (int s = 0; s < 16; s++) { h[s] = 0.f; p[s] = 1.f; }

    const size_t rowbase = (size_t)b * LL + c * CHUNK;
    for (int t0 = 0; t0 < CHUNK; t0 += TT) {
        #pragma unroll
        for (int pp = 0; pp < 4; pp++) {
            int r0 = (pp * 4 + w) * 2;
            size_t grow = rowbase + t0 + r0 + lrow;
            gld_lds16(dty + grow * DI + d0 + lcol, &sdt[r0][0]);
            gld_lds16(xc  + grow * DI + d0 + lcol, &su[r0][0]);
        }
        gld_lds16(xdbl + (rowbase + t0 + w * 8 + brow) * 96 + DTR + bcol,
                  &sBC[w * 8][0]);
        __syncthreads();
        for (int t = 0; t < TT; t++) {
            float dtv = b2f(sdt[t][tid]);
            float uv  = b2f(su[t][tid]);
            float tmp = dtv * uv;
            const float4* bc = (const float4*)&sBC[t][0];
            float4 B0 = bc[0], B1 = bc[1], B2 = bc[2], B3 = bc[3];
            float Bv[16] = {B0.x,B0.y,B0.z,B0.w, B1.x,B1.y,B1.z,B1.w,
                            B2.x,B2.y,B2.z,B2.w, B3.x,B3.y,B3.z,B3.w};
            #pragma unroll
            for (int s = 0; s < 16; s++) {
                float dA = __expf(dtv * Ads[s]);
                h[s] = dA * h[s] + tmp * Bv[s];
                p[s] *= dA;
            }
        }
        __syncthreads();
    }
    size_t o = ((size_t)(b * NC + c) * DI + d) * DS;
    #pragma unroll
    for (int q = 0; q < 4; q++) {
        *(float4*)&P[o + q*4] = make_float4(p[q*4], p[q*4+1], p[q*4+2], p[q*4+3]);
        *(float4*)&S[o + q*4] = make_float4(h[q*4], h[q*4+1], h[q*4+2], h[q*4+3]);
    }
}

// Phase 2: fold chunk summaries; writes entry state h_in in-place over S.
__global__ __launch_bounds__(256) void scan_combine(
    const float* __restrict__ P, float* __restrict__ S)
{
    int g = blockIdx.x * 256 + threadIdx.x;   // B*DI*DS threads
    int b = g >> 15;                          // DI*DS = 32768
    int rem = g & 32767;
    float h = 0.f;
    #pragma unroll
    for (int c = 0; c < NC; c++) {
        size_t o = ((size_t)(b * NC + c) << 15) + rem;
        float p = P[o], sv = S[o];
        S[o] = h;                             // h_in for chunk c
        h = p * h + sv;
    }
}

// Phase 3: full scan per chunk starting from h_in; y + D-skip + z-gate.
__global__ __launch_bounds__(256) void scan_part2(
    const float* __restrict__ xdbl, bf16* __restrict__ dty,
    const bf16* __restrict__ xc, const bf16* __restrict__ xz,
    const float* __restrict__ A_log, const float* __restrict__ Dp,
    const float* __restrict__ Hin)
{
    __shared__ bf16 sdt[TT][TCH];
    __shared__ bf16 su[TT][TCH];
    __shared__ bf16 sz[TT][TCH];
    __shared__ alignas(16) float sBC[TT][32];
    int bid = blockIdx.x;
    int cg = bid & 7;
    int c  = (bid >> 3) & (NC - 1);
    int b  = bid >> 7;
    int d0 = cg * TCH;
    int tid = threadIdx.x;
    int w = tid >> 6, l = tid & 63;
    int lrow = l >> 5, lcol = (l & 31) * 8;
    int brow = l >> 3, bcol = (l & 7) * 4;
    int d = d0 + tid;

    float Ads[16];
    #pragma unroll
    for (int q = 0; q < 4; q++) {
        float4 a4 = *(const float4*)&A_log[(size_t)d * DS + q * 4];
        Ads[q*4+0] = -__expf(a4.x); Ads[q*4+1] = -__expf(a4.y);
        Ads[q*4+2] = -__expf(a4.z); Ads[q*4+3] = -__expf(a4.w);
    }
    float h[16];
    size_t ho = ((size_t)(b * NC + c) * DI + d) * DS;
    #pragma unroll
    for (int q = 0; q < 4; q++) {
        float4 hv = *(const float4*)&Hin[ho + q*4];
        h[q*4] = hv.x; h[q*4+1] = hv.y; h[q*4+2] = hv.z; h[q*4+3] = hv.w;
    }
    float dpd = Dp[d];

    const size_t rowbase = (size_t)b * LL + c * CHUNK;
    for (int t0 = 0; t0 < CHUNK; t0 += TT) {
        #pragma unroll
        for (int pp = 0; pp < 4; pp++) {
            int r0 = (pp * 4 + w) * 2;
            size_t grow = rowbase + t0 + r0 + lrow;
            gld_lds16(dty + grow * DI + d0 + lcol, &sdt[r0][0]);
            gld_lds16(xc  + grow * DI + d0 + lcol, &su[r0][0]);
            gld_lds16(xz  + grow * (2 * DI) + DI + d0 + lcol, &sz[r0][0]);
        }
        gld_lds16(xdbl + (rowbase + t0 + w * 8 + brow) * 96 + DTR + bcol,
                  &sBC[w * 8][0]);
        __syncthreads();
        for (int t = 0; t < TT; t++) {
            float dtv = b2f(sdt[t][tid]);
            float uv  = b2f(su[t][tid]);
            float tmp = dtv * uv;
            const float4* bc = (const float4*)&sBC[t][0];
            float4 B0 = bc[0], B1 = bc[1], B2 = bc[2], B3 = bc[3];
            float4 C0 = bc[4], C1 = bc[5], C2 = bc[6], C3 = bc[7];
            float Bv[16] = {B0.x,B0.y,B0.z,B0.w, B1.x,B1.y,B1.z,B1.w,
                            B2.x,B2.y,B2.z,B2.w, B3.x,B3.y,B3.z,B3.w};
            float Cv[16] = {C0.x,C0.y,C0.z,C0.w, C1.x,C1.y,C1.z,C1.w,
                            C2.x,C2.y,C2.z,C2.w, C3.x,C3.y,C3.z,C3.w};
            float y = 0.f;
            #pragma unroll
            for (int s = 0; s < 16; s++) {
                float dA = __expf(dtv * Ads[s]);
                h[s] = dA * h[s] + tmp * Bv[s];
                y = fmaf(h[s], Cv[s], y);
            }
            float zv = b2f(sz[t][tid]);
            float yo = (y + uv * dpd) * (zv / (1.f + __expf(-zv)));
            dty[(rowbase + t0 + t) * DI + d] = f2b(yo);
        }
        __syncthreads();
    }
}

// ---------------- Monolithic scan (fallback when ws is small) ----------------
__global__ __launch_bounds__(256) void scan_mono(
    const float* __restrict__ xdbl, bf16* __restrict__ dty,
    const bf16* __restrict__ xc, const bf16* __restrict__ xz,
    const float* __restrict__ A_log, const float* __restrict__ Dp)
{
    const int TC = 64;
    int b = blockIdx.x >> 7;
    int dblk = blockIdx.x & 127;
    int d0 = dblk * 16;
    int tid = threadIdx.x;
    int s = tid & 15;
    int dg = tid >> 4;
    int d = d0 + dg;
    float Ads = -__expf(A_log[(size_t)d * DS + s]);
    float h = 0.f;
    __shared__ float sdt[TC][16], su[TC][16], sB[TC][16], sC[TC][16], sy[TC][16];
    const size_t rowbase = (size_t)b * LL;
    int wi = tid >> 2;
    int wj = (tid & 3) * 4;
    float4 dpv = *(const float4*)(Dp + d0 + wj);
    for (int t0 = 0; t0 < LL; t0 += TC) {
        {
            size_t g = (rowbase + t0 + wi) * (size_t)DI + d0 + wj;
            *(float4*)&sdt[wi][wj] = ld4(dty + g);
            *(float4*)&su[wi][wj]  = ld4(xc + g);
        }
        #pragma unroll
        for (int r = 0; r < 4; r++) {
            int i = (tid >> 4) + r * 16;
            size_t g = (rowbase + t0 + i) * 96;
            sB[i][s] = xdbl[g + DTR + s];
            sC[i][s] = xdbl[g + DTR + DS + s];
        }
        __syncthreads();
        for (int i = 0; i < TC; i++) {
            float dtv = sdt[i][dg];
            float dA = __expf(dtv * Ads);
            h = dA * h + dtv * su[i][dg] * sB[i][s];
            float yp = h * sC[i][s];
            yp += __shfl_xor(yp, 1);
            yp += __shfl_xor(yp, 2);
            yp += __shfl_xor(yp, 4);
            yp += __shfl_xor(yp, 8);
            if (s == 0) sy[i][dg] = yp;
        }
        __syncthreads();
        {
            size_t g  = (rowbase + t0 + wi) * (size_t)DI + d0 + wj;
            size_t gz = (rowbase + t0 + wi) * (size_t)(2 * DI) + DI + d0 + wj;
            float4 zv = ld4(xz + gz);
            float4 yv = *(const float4*)&sy[wi][wj];
            float4 uv = *(const float4*)&su[wi][wj];
            ushort4 o;
            o.x = f2b((yv.x + uv.x * dpv.x) * (zv.x / (1.f + __expf(-zv.x))));
            o.y = f2b((yv.y + uv.y * dpv.y) * (zv.y / (1.f + __expf(-zv.y))));
            o.z = f2b((yv.z + uv.z * dpv.z) * (zv.z / (1.f + __expf(-zv.z))));
            o.w = f2b((yv.w + uv.w * dpv.w) * (zv.w / (1.f + __expf(-zv.w))));
            *(ushort4*)(dty + g) = o;
        }
        __syncthreads();
    }
}

// ---------------------------------------------------------------------------
extern "C" void kernel_launch(void* const* d_in, const int* in_sizes, int n_in,
                              void* d_out, int out_size, void* d_ws, size_t ws_size,
                              hipStream_t stream)
{
    const float* x      = (const float*)d_in[0];
    const float* ln_w   = (const float*)d_in[1];
    const float* ln_b   = (const float*)d_in[2];
    const float* W_in   = (const float*)d_in[3];
    const float* conv_w = (const float*)d_in[4];
    const float* conv_b = (const float*)d_in[5];
    const float* W_x    = (const float*)d_in[6];
    const float* W_dt   = (const float*)d_in[7];
    const float* b_dt   = (const float*)d_in[8];
    const float* A_log  = (const float*)d_in[9];
    const float* Dp     = (const float*)d_in[10];
    const float* W_out  = (const float*)d_in[11];
    float* out = (float*)d_out;

    const size_t R = (size_t)BB * LL;   // 8192 rows

    // ws: xz bf16 64MB | dty bf16 32MB | xdbl f32 3MB | P,S f32 8MB each
    bf16*  xz    = (bf16*)d_ws;                    // R * 2*DI
    bf16*  dty   = xz + R * 2 * DI;                // R * DI
    float* xdbl  = (float*)(dty + R * DI);         // R * 96
    float* Pbuf  = xdbl + R * 96;                  // B*NC*DI*DS
    float* Sbuf  = Pbuf + (size_t)BB * NC * DI * DS;
    const size_t ws_need = (size_t)((char*)(Sbuf + (size_t)BB * NC * DI * DS) - (char*)d_ws);
    const bool chunked = ws_size >= ws_need;

    bf16*  W_in_b  = dty;   // dead before dt-gemm writes dty
    bf16*  W_out_b = xz;    // converted AFTER scan consumed z

    bf16* xn = (bf16*)d_out;
    bf16* xc = (bf16*)d_out;

    // 0. weight convert (W_in)
    f2b_kernel<<<(2 * DI * DM / 4) / 256, 256, 0, stream>>>(W_in, W_in_b, 2 * DI * DM / 4);

    // 1. LayerNorm -> xn bf16
    ln_kernel<<<(int)R, 256, 0, stream>>>(x, ln_w, ln_b, xn);

    // 2. in_proj (MFMA): xz[8192,4096] = xn @ W_in^T
    gemm_mfma<0, bf16><<<dim3(2 * DI / 128, R / 128), 256, 0, stream>>>(
        xn, DM, W_in_b, DM, xz, 2 * DI, DM, nullptr);

    // 3. conv + SiLU -> xc
    conv_silu_kernel<<<(int)(R * DI / 4 / 256), 256, 0, stream>>>(
        xz, conv_w, conv_b, xc);

    // 4a. x_proj: xdbl[8192,96] = xc @ W_x^T   (f32)
    gemm_nt<0><<<dim3(2, R / 64), 256, 0, stream>>>(
        xc, DI, W_x, DI, xdbl, 96, (int)R, 96, DI, nullptr);

    // 4b. dt = softplus(xdbl[:,:64] @ W_dt^T + b_dt) -> dty bf16
    gemm_nt<1><<<dim3(DI / 64, R / 64), 256, 0, stream>>>(
        xdbl, 96, W_dt, DTR, dty, DI, (int)R, DI, DTR, b_dt);

    // 5. selective scan + D-skip + z-gate (y overwrites dty)
    if (chunked) {
        scan_part1<<<BB * NC * (DI / TCH), 256, 0, stream>>>(
            xdbl, dty, xc, A_log, Pbuf, Sbuf);
        scan_combine<<<BB * DI * DS / 256, 256, 0, stream>>>(Pbuf, Sbuf);
        scan_part2<<<BB * NC * (DI / TCH), 256, 0, stream>>>(
            xdbl, dty, xc, xz, A_log, Dp, Sbuf);
    } else {
        scan_mono<<<BB * (DI / 16), 256, 0, stream>>>(
            xdbl, dty, xc, xz, A_log, Dp);
    }

    // 5b. weight convert (W_out) into xz head (z now dead)
    f2b_kernel<<<(DM * DI / 4) / 256, 256, 0, stream>>>(W_out, W_out_b, DM * DI / 4);

    // 6. out_proj (MFMA) + residual: out = y @ W_out^T + x
    gemm_mfma<2, float><<<dim3(DM / 128, R / 128), 256, 0, stream>>>(
        dty, DI, W_out_b, DI, out, DM, DI, x);
}

// Round 6
// 709.595 us; speedup vs baseline: 3.2609x; 1.0487x over previous
//
#include <hip/hip_runtime.h>
#include <math.h>

#define BB 4
#define LL 2048
#define DM 1024
#define DI 2048
#define DS 16
#define DTR 64
#define NC 16            // scan chunks per sequence
#define CHUNK (LL / NC)  // 128
#define TCH 256          // channels per scan block
#define TT 32            // timesteps per staged tile

typedef unsigned short bf16;
typedef __attribute__((ext_vector_type(8))) short bf16x8;
typedef __attribute__((ext_vector_type(4))) float f32x4;

__device__ inline float b2f(bf16 u) { return __uint_as_float(((unsigned)u) << 16); }
__device__ inline bf16 f2b(float f) {
    unsigned u = __float_as_uint(f);
    u += 0x7FFF + ((u >> 16) & 1);   // round-to-nearest-even
    return (bf16)(u >> 16);
}

__device__ inline float4 ld4(const float* p) { return *(const float4*)p; }
__device__ inline float4 ld4(const bf16* p) {
    ushort4 v = *(const ushort4*)p;
    return make_float4(b2f(v.x), b2f(v.y), b2f(v.z), b2f(v.w));
}
__device__ inline void st1(float* p, float v) { *p = v; }
__device__ inline void st1(bf16* p, float v) { *p = f2b(v); }

// async global->LDS, 16 bytes per lane; LDS dest = wave-uniform base + lane*16
__device__ inline void gld_lds16(const void* g, void* l) {
    __builtin_amdgcn_global_load_lds(
        (const __attribute__((address_space(1))) unsigned int*)g,
        (__attribute__((address_space(3))) unsigned int*)l, 16, 0, 0);
}

// ---------------- f32 -> bf16 convert (weights) ------------------------------
__global__ __launch_bounds__(256) void f2b_kernel(const float* __restrict__ in,
    bf16* __restrict__ out, int n4)
{
    int i = blockIdx.x * 256 + threadIdx.x;
    if (i >= n4) return;
    float4 v = *(const float4*)(in + (size_t)i * 4);
    ushort4 o = { f2b(v.x), f2b(v.y), f2b(v.z), f2b(v.w) };
    *(ushort4*)(out + (size_t)i * 4) = o;
}

// ---------------- LayerNorm: one block per row, bf16 out ---------------------
__global__ __launch_bounds__(256) void ln_kernel(const float* __restrict__ x,
    const float* __restrict__ w, const float* __restrict__ b,
    bf16* __restrict__ xn)
{
    int row = blockIdx.x;
    int tid = threadIdx.x;
    const float* xr = x + (size_t)row * DM;
    float4 v = *(const float4*)(xr + tid * 4);
    float s1 = v.x + v.y + v.z + v.w;
    float s2 = v.x * v.x + v.y * v.y + v.z * v.z + v.w * v.w;
    #pragma unroll
    for (int o = 32; o > 0; o >>= 1) {
        s1 += __shfl_xor(s1, o);
        s2 += __shfl_xor(s2, o);
    }
    __shared__ float r1[4], r2[4];
    __shared__ float smu, srs;
    int wv = tid >> 6;
    if ((tid & 63) == 0) { r1[wv] = s1; r2[wv] = s2; }
    __syncthreads();
    if (tid == 0) {
        float t1 = r1[0] + r1[1] + r1[2] + r1[3];
        float t2 = r2[0] + r2[1] + r2[2] + r2[3];
        float mu = t1 * (1.0f / DM);
        float var = t2 * (1.0f / DM) - mu * mu;
        smu = mu;
        srs = rsqrtf(var + 1e-5f);
    }
    __syncthreads();
    float mu = smu, rs = srs;
    float4 wv4 = *(const float4*)(w + tid * 4);
    float4 bv4 = *(const float4*)(b + tid * 4);
    ushort4 o;
    o.x = f2b((v.x - mu) * rs * wv4.x + bv4.x);
    o.y = f2b((v.y - mu) * rs * wv4.y + bv4.y);
    o.z = f2b((v.z - mu) * rs * wv4.z + bv4.z);
    o.w = f2b((v.w - mu) * rs * wv4.w + bv4.w);
    *(ushort4*)(xn + (size_t)row * DM + tid * 4) = o;
}

// ---------------- MFMA bf16 GEMM, NT: C[m,n] = sum_k A[m,k]*B[n,k] ----------
// 128x128 tile, BK=32. EPI 0: plain. EPI 1: softplus(acc+aux[n]).
// EPI 2: acc + aux[m*ldc+n].
template<int EPI, typename TC>
__global__ __launch_bounds__(256) void gemm_mfma(
    const bf16* __restrict__ A, int lda,
    const bf16* __restrict__ B, int ldb,
    TC* __restrict__ C, int ldc,
    int K, const float* __restrict__ aux)
{
    __shared__ bf16 As[128 * 32];
    __shared__ bf16 Bs[128 * 32];
    const int tid = threadIdx.x;
    const int lane = tid & 63;
    const int w = tid >> 6;
    const int wm = w >> 1, wn = w & 1;
    const int m0 = blockIdx.y * 128, n0 = blockIdx.x * 128;

    const int srow = lane >> 2;
    const int schunk = (lane & 3) * 8;

    const int fm = lane & 15;
    const int fq = lane >> 4;

    f32x4 acc[4][4] = {};

    for (int kt = 0; kt < K; kt += 32) {
        #pragma unroll
        for (int i = 0; i < 2; i++) {
            int r0 = i * 64 + w * 16;
            gld_lds16(A + (size_t)(m0 + r0 + srow) * lda + kt + schunk, &As[r0 * 32]);
            gld_lds16(B + (size_t)(n0 + r0 + srow) * ldb + kt + schunk, &Bs[r0 * 32]);
        }
        __syncthreads();
        bf16x8 af[4], bfr[4];
        #pragma unroll
        for (int i = 0; i < 4; i++) {
            af[i]  = *(const bf16x8*)&As[(wm * 64 + i * 16 + fm) * 32 + fq * 8];
            bfr[i] = *(const bf16x8*)&Bs[(wn * 64 + i * 16 + fm) * 32 + fq * 8];
        }
        #pragma unroll
        for (int i = 0; i < 4; i++)
            #pragma unroll
            for (int j = 0; j < 4; j++)
                acc[i][j] = __builtin_amdgcn_mfma_f32_16x16x32_bf16(
                    af[i], bfr[j], acc[i][j], 0, 0, 0);
        __syncthreads();
    }

    #pragma unroll
    for (int i = 0; i < 4; i++) {
        #pragma unroll
        for (int r = 0; r < 4; r++) {
            int m = m0 + wm * 64 + i * 16 + fq * 4 + r;
            #pragma unroll
            for (int j = 0; j < 4; j++) {
                int n = n0 + wn * 64 + j * 16 + fm;
                float v = acc[i][j][r];
                if (EPI == 1) {
                    v += aux[n];
                    v = (v > 20.f) ? v : log1pf(__expf(v));
                } else if (EPI == 2) {
                    v += aux[(size_t)m * ldc + n];
                }
                st1(&C[(size_t)m * ldc + n], v);
            }
        }
    }
}

// ---------------- x_proj MFMA: xdbl[R,96] = xc[R,DI] @ W_x[96,DI]^T ----------
// 32-row M tile (grid R/32 = 256), waves 2m x 2n, each 16 rows x 48 cols.
// Also emits bf16 copy of cols 0..63 (dt_r) for the dt GEMM.
__global__ __launch_bounds__(256) void xproj_mfma(
    const bf16* __restrict__ A,      // xc [R, DI]
    const bf16* __restrict__ Bm,     // W_x bf16, padded to 128 rows [128, DI]
    float* __restrict__ Cx,          // xdbl [R, 96]
    bf16* __restrict__ dtr)          // [R, 64]
{
    __shared__ bf16 As[32 * 32];
    __shared__ bf16 Bs[128 * 32];
    const int tid = threadIdx.x;
    const int lane = tid & 63;
    const int w = tid >> 6;
    const int wm = w >> 1, wn = w & 1;
    const int m0 = blockIdx.x * 32;
    const int srow = lane >> 2;
    const int schunk = (lane & 3) * 8;
    const int fm = lane & 15;
    const int fq = lane >> 4;
    f32x4 acc[3] = {};
    for (int kt = 0; kt < DI; kt += 32) {
        if (w < 2) {
            int r0 = w * 16;
            gld_lds16(A + (size_t)(m0 + r0 + srow) * DI + kt + schunk, &As[r0 * 32]);
        }
        {
            int r0 = w * 32;
            gld_lds16(Bm + (size_t)(r0 + srow) * DI + kt + schunk, &Bs[r0 * 32]);
            gld_lds16(Bm + (size_t)(r0 + 16 + srow) * DI + kt + schunk, &Bs[(r0 + 16) * 32]);
        }
        __syncthreads();
        bf16x8 af = *(const bf16x8*)&As[(wm * 16 + fm) * 32 + fq * 8];
        #pragma unroll
        for (int j = 0; j < 3; j++) {
            bf16x8 bf = *(const bf16x8*)&Bs[((wn * 3 + j) * 16 + fm) * 32 + fq * 8];
            acc[j] = __builtin_amdgcn_mfma_f32_16x16x32_bf16(af, bf, acc[j], 0, 0, 0);
        }
        __syncthreads();
    }
    #pragma unroll
    for (int j = 0; j < 3; j++) {
        int col = (wn * 3 + j) * 16 + fm;
        #pragma unroll
        for (int r = 0; r < 4; r++) {
            int m = m0 + wm * 16 + fq * 4 + r;
            float v = acc[j][r];
            Cx[(size_t)m * 96 + col] = v;
            if (col < 64) dtr[(size_t)m * 64 + col] = f2b(v);
        }
    }
}

// ---------------- Tiled f32-compute GEMM (fallback path only) ----------------
template<int EPI, typename TA, typename TB, typename TC>
__global__ __launch_bounds__(256) void gemm_nt(
    const TA* __restrict__ A, int lda,
    const TB* __restrict__ B, int ldb,
    TC* __restrict__ C, int ldc,
    int M, int N, int K,
    const float* __restrict__ aux)
{
    __shared__ float As[16][64];
    __shared__ float Bs[16][64];
    int tid = threadIdx.x;
    int m0 = blockIdx.y * 64, n0 = blockIdx.x * 64;
    int lr = tid >> 2;
    int lc = (tid & 3) * 4;
    int tm = tid >> 4;
    int tn = tid & 15;
    float acc[4][4] = {};
    for (int kt = 0; kt < K; kt += 16) {
        float4 av = ld4(A + (size_t)(m0 + lr) * lda + kt + lc);
        float4 bv = make_float4(0.f, 0.f, 0.f, 0.f);
        if (n0 + lr < N)
            bv = ld4(B + (size_t)(n0 + lr) * ldb + kt + lc);
        As[lc + 0][lr] = av.x; As[lc + 1][lr] = av.y;
        As[lc + 2][lr] = av.z; As[lc + 3][lr] = av.w;
        Bs[lc + 0][lr] = bv.x; Bs[lc + 1][lr] = bv.y;
        Bs[lc + 2][lr] = bv.z; Bs[lc + 3][lr] = bv.w;
        __syncthreads();
        #pragma unroll
        for (int k = 0; k < 16; k++) {
            float4 a4 = *(const float4*)&As[k][tm * 4];
            float4 b4 = *(const float4*)&Bs[k][tn * 4];
            float am[4] = {a4.x, a4.y, a4.z, a4.w};
            float bn[4] = {b4.x, b4.y, b4.z, b4.w};
            #pragma unroll
            for (int i = 0; i < 4; i++)
                #pragma unroll
                for (int j = 0; j < 4; j++)
                    acc[i][j] = fmaf(am[i], bn[j], acc[i][j]);
        }
        __syncthreads();
    }
    #pragma unroll
    for (int i = 0; i < 4; i++) {
        int m = m0 + tm * 4 + i;
        #pragma unroll
        for (int j = 0; j < 4; j++) {
            int n = n0 + tn * 4 + j;
            if (n >= N) continue;
            float v = acc[i][j];
            if (EPI == 1) {
                v += aux[n];
                v = (v > 20.f) ? v : log1pf(__expf(v));
            }
            st1(&C[(size_t)m * ldc + n], v);
        }
    }
}

// ---------------- Depthwise causal conv (4 taps) + SiLU ----------------------
__global__ __launch_bounds__(256) void conv_silu_kernel(
    const bf16* __restrict__ xz, const float* __restrict__ cw,
    const float* __restrict__ cb, bf16* __restrict__ xc)
{
    int idx = blockIdx.x * 256 + threadIdx.x;
    int d4 = idx & (DI / 4 - 1);
    int bl = idx >> 9;
    int l = bl & (LL - 1);
    int d0 = d4 * 4;
    float4 bias = *(const float4*)(cb + d0);
    float acc[4] = {bias.x, bias.y, bias.z, bias.w};
    #pragma unroll
    for (int k = 0; k < 4; k++) {
        int lp = l - 3 + k;
        if (lp < 0) continue;
        float4 xv = ld4(xz + (size_t)(bl - 3 + k) * (2 * DI) + d0);
        acc[0] = fmaf(xv.x, cw[(d0 + 0) * 4 + k], acc[0]);
        acc[1] = fmaf(xv.y, cw[(d0 + 1) * 4 + k], acc[1]);
        acc[2] = fmaf(xv.z, cw[(d0 + 2) * 4 + k], acc[2]);
        acc[3] = fmaf(xv.w, cw[(d0 + 3) * 4 + k], acc[3]);
    }
    ushort4 o;
    o.x = f2b(acc[0] / (1.f + __expf(-acc[0])));
    o.y = f2b(acc[1] / (1.f + __expf(-acc[1])));
    o.z = f2b(acc[2] / (1.f + __expf(-acc[2])));
    o.w = f2b(acc[3] / (1.f + __expf(-acc[3])));
    *(ushort4*)(xc + (size_t)bl * DI + d0) = o;
}

// ---------------- Chunked selective scan, thread-per-channel -----------------
__global__ __launch_bounds__(256) void scan_part1(
    const float* __restrict__ xdbl, const bf16* __restrict__ dty,
    const bf16* __restrict__ xc, const float* __restrict__ A_log,
    float* __restrict__ P, float* __restrict__ S)
{
    __shared__ bf16 sdt[TT][TCH];
    __shared__ bf16 su[TT][TCH];
    __shared__ alignas(16) float sBC[TT][32];
    int bid = blockIdx.x;
    int cg = bid & 7;                 // DI/TCH = 8
    int c  = (bid >> 3) & (NC - 1);
    int b  = bid >> 7;
    int d0 = cg * TCH;
    int tid = threadIdx.x;
    int w = tid >> 6, l = tid & 63;
    int lrow = l >> 5, lcol = (l & 31) * 8;
    int brow = l >> 3, bcol = (l & 7) * 4;
    int d = d0 + tid;

    float Ads[16];
    #pragma unroll
    for (int q = 0; q < 4; q++) {
        float4 a4 = *(const float4*)&A_log[(size_t)d * DS + q * 4];
        Ads[q*4+0] = -__expf(a4.x); Ads[q*4+1] = -__expf(a4.y);
        Ads[q*4+2] = -__expf(a4.z); Ads[q*4+3] = -__expf(a4.w);
    }
    float h[16], p[16];
    #pragma unroll
    for (int s = 0; s < 16; s++) { h[s] = 0.f; p[s] = 1.f; }

    const size_t rowbase = (size_t)b * LL + c * CHUNK;
    for (int t0 = 0; t0 < CHUNK; t0 += TT) {
        #pragma unroll
        for (int pp = 0; pp < 4; pp++) {
            int r0 = (pp * 4 + w) * 2;
            size_t grow = rowbase + t0 + r0 + lrow;
            gld_lds16(dty + grow * DI + d0 + lcol, &sdt[r0][0]);
            gld_lds16(xc  + grow * DI + d0 + lcol, &su[r0][0]);
        }
        gld_lds16(xdbl + (rowbase + t0 + w * 8 + brow) * 96 + DTR + bcol,
                  &sBC[w * 8][0]);
        __syncthreads();
        for (int t = 0; t < TT; t++) {
            float dtv = b2f(sdt[t][tid]);
            float uv  = b2f(su[t][tid]);
            float tmp = dtv * uv;
            const float4* bc = (const float4*)&sBC[t][0];
            float4 B0 = bc[0], B1 = bc[1], B2 = bc[2], B3 = bc[3];
            float Bv[16] = {B0.x,B0.y,B0.z,B0.w, B1.x,B1.y,B1.z,B1.w,
                            B2.x,B2.y,B2.z,B2.w, B3.x,B3.y,B3.z,B3.w};
            #pragma unroll
            for (int s = 0; s < 16; s++) {
                float dA = __expf(dtv * Ads[s]);
                h[s] = dA * h[s] + tmp * Bv[s];
                p[s] *= dA;
            }
        }
        __syncthreads();
    }
    size_t o = ((size_t)(b * NC + c) * DI + d) * DS;
    #pragma unroll
    for (int q = 0; q < 4; q++) {
        *(float4*)&P[o + q*4] = make_float4(p[q*4], p[q*4+1], p[q*4+2], p[q*4+3]);
        *(float4*)&S[o + q*4] = make_float4(h[q*4], h[q*4+1], h[q*4+2], h[q*4+3]);
    }
}

__global__ __launch_bounds__(256) void scan_combine(
    const float* __restrict__ P, float* __restrict__ S)
{
    int g = blockIdx.x * 256 + threadIdx.x;   // B*DI*DS threads
    int b = g >> 15;                          // DI*DS = 32768
    int rem = g & 32767;
    float h = 0.f;
    #pragma unroll
    for (int c = 0; c < NC; c++) {
        size_t o = ((size_t)(b * NC + c) << 15) + rem;
        float p = P[o], sv = S[o];
        S[o] = h;                             // h_in for chunk c
        h = p * h + sv;
    }
}

__global__ __launch_bounds__(256) void scan_part2(
    const float* __restrict__ xdbl, bf16* __restrict__ dty,
    const bf16* __restrict__ xc, const bf16* __restrict__ xz,
    const float* __restrict__ A_log, const float* __restrict__ Dp,
    const float* __restrict__ Hin)
{
    __shared__ bf16 sdt[TT][TCH];
    __shared__ bf16 su[TT][TCH];
    __shared__ bf16 sz[TT][TCH];
    __shared__ alignas(16) float sBC[TT][32];
    int bid = blockIdx.x;
    int cg = bid & 7;
    int c  = (bid >> 3) & (NC - 1);
    int b  = bid >> 7;
    int d0 = cg * TCH;
    int tid = threadIdx.x;
    int w = tid >> 6, l = tid & 63;
    int lrow = l >> 5, lcol = (l & 31) * 8;
    int brow = l >> 3, bcol = (l & 7) * 4;
    int d = d0 + tid;

    float Ads[16];
    #pragma unroll
    for (int q = 0; q < 4; q++) {
        float4 a4 = *(const float4*)&A_log[(size_t)d * DS + q * 4];
        Ads[q*4+0] = -__expf(a4.x); Ads[q*4+1] = -__expf(a4.y);
        Ads[q*4+2] = -__expf(a4.z); Ads[q*4+3] = -__expf(a4.w);
    }
    float h[16];
    size_t ho = ((size_t)(b * NC + c) * DI + d) * DS;
    #pragma unroll
    for (int q = 0; q < 4; q++) {
        float4 hv = *(const float4*)&Hin[ho + q*4];
        h[q*4] = hv.x; h[q*4+1] = hv.y; h[q*4+2] = hv.z; h[q*4+3] = hv.w;
    }
    float dpd = Dp[d];

    const size_t rowbase = (size_t)b * LL + c * CHUNK;
    for (int t0 = 0; t0 < CHUNK; t0 += TT) {
        #pragma unroll
        for (int pp = 0; pp < 4; pp++) {
            int r0 = (pp * 4 + w) * 2;
            size_t grow = rowbase + t0 + r0 + lrow;
            gld_lds16(dty + grow * DI + d0 + lcol, &sdt[r0][0]);
            gld_lds16(xc  + grow * DI + d0 + lcol, &su[r0][0]);
            gld_lds16(xz  + grow * (2 * DI) + DI + d0 + lcol, &sz[r0][0]);
        }
        gld_lds16(xdbl + (rowbase + t0 + w * 8 + brow) * 96 + DTR + bcol,
                  &sBC[w * 8][0]);
        __syncthreads();
        for (int t = 0; t < TT; t++) {
            float dtv = b2f(sdt[t][tid]);
            float uv  = b2f(su[t][tid]);
            float tmp = dtv * uv;
            const float4* bc = (const float4*)&sBC[t][0];
            float4 B0 = bc[0], B1 = bc[1], B2 = bc[2], B3 = bc[3];
            float4 C0 = bc[4], C1 = bc[5], C2 = bc[6], C3 = bc[7];
            float Bv[16] = {B0.x,B0.y,B0.z,B0.w, B1.x,B1.y,B1.z,B1.w,
                            B2.x,B2.y,B2.z,B2.w, B3.x,B3.y,B3.z,B3.w};
            float Cv[16] = {C0.x,C0.y,C0.z,C0.w, C1.x,C1.y,C1.z,C1.w,
                            C2.x,C2.y,C2.z,C2.w, C3.x,C3.y,C3.z,C3.w};
            float y = 0.f;
            #pragma unroll
            for (int s = 0; s < 16; s++) {
                float dA = __expf(dtv * Ads[s]);
                h[s] = dA * h[s] + tmp * Bv[s];
                y = fmaf(h[s], Cv[s], y);
            }
            float zv = b2f(sz[t][tid]);
            float yo = (y + uv * dpd) * (zv / (1.f + __expf(-zv)));
            dty[(rowbase + t0 + t) * DI + d] = f2b(yo);
        }
        __syncthreads();
    }
}

// ---------------- Monolithic scan (fallback when ws is small) ----------------
__global__ __launch_bounds__(256) void scan_mono(
    const float* __restrict__ xdbl, bf16* __restrict__ dty,
    const bf16* __restrict__ xc, const bf16* __restrict__ xz,
    const float* __restrict__ A_log, const float* __restrict__ Dp)
{
    const int TC = 64;
    int b = blockIdx.x >> 7;
    int dblk = blockIdx.x & 127;
    int d0 = dblk * 16;
    int tid = threadIdx.x;
    int s = tid & 15;
    int dg = tid >> 4;
    int d = d0 + dg;
    float Ads = -__expf(A_log[(size_t)d * DS + s]);
    float h = 0.f;
    __shared__ float sdt[TC][16], su[TC][16], sB[TC][16], sC[TC][16], sy[TC][16];
    const size_t rowbase = (size_t)b * LL;
    int wi = tid >> 2;
    int wj = (tid & 3) * 4;
    float4 dpv = *(const float4*)(Dp + d0 + wj);
    for (int t0 = 0; t0 < LL; t0 += TC) {
        {
            size_t g = (rowbase + t0 + wi) * (size_t)DI + d0 + wj;
            *(float4*)&sdt[wi][wj] = ld4(dty + g);
            *(float4*)&su[wi][wj]  = ld4(xc + g);
        }
        #pragma unroll
        for (int r = 0; r < 4; r++) {
            int i = (tid >> 4) + r * 16;
            size_t g = (rowbase + t0 + i) * 96;
            sB[i][s] = xdbl[g + DTR + s];
            sC[i][s] = xdbl[g + DTR + DS + s];
        }
        __syncthreads();
        for (int i = 0; i < TC; i++) {
            float dtv = sdt[i][dg];
            float dA = __expf(dtv * Ads);
            h = dA * h + dtv * su[i][dg] * sB[i][s];
            float yp = h * sC[i][s];
            yp += __shfl_xor(yp, 1);
            yp += __shfl_xor(yp, 2);
            yp += __shfl_xor(yp, 4);
            yp += __shfl_xor(yp, 8);
            if (s == 0) sy[i][dg] = yp;
        }
        __syncthreads();
        {
            size_t g  = (rowbase + t0 + wi) * (size_t)DI + d0 + wj;
            size_t gz = (rowbase + t0 + wi) * (size_t)(2 * DI) + DI + d0 + wj;
            float4 zv = ld4(xz + gz);
            float4 yv = *(const float4*)&sy[wi][wj];
            float4 uv = *(const float4*)&su[wi][wj];
            ushort4 o;
            o.x = f2b((yv.x + uv.x * dpv.x) * (zv.x / (1.f + __expf(-zv.x))));
            o.y = f2b((yv.y + uv.y * dpv.y) * (zv.y / (1.f + __expf(-zv.y))));
            o.z = f2b((yv.z + uv.z * dpv.z) * (zv.z / (1.f + __expf(-zv.z))));
            o.w = f2b((yv.w + uv.w * dpv.w) * (zv.w / (1.f + __expf(-zv.w))));
            *(ushort4*)(dty + g) = o;
        }
        __syncthreads();
    }
}

// ---------------------------------------------------------------------------
extern "C" void kernel_launch(void* const* d_in, const int* in_sizes, int n_in,
                              void* d_out, int out_size, void* d_ws, size_t ws_size,
                              hipStream_t stream)
{
    const float* x      = (const float*)d_in[0];
    const float* ln_w   = (const float*)d_in[1];
    const float* ln_b   = (const float*)d_in[2];
    const float* W_in   = (const float*)d_in[3];
    const float* conv_w = (const float*)d_in[4];
    const float* conv_b = (const float*)d_in[5];
    const float* W_x    = (const float*)d_in[6];
    const float* W_dt   = (const float*)d_in[7];
    const float* b_dt   = (const float*)d_in[8];
    const float* A_log  = (const float*)d_in[9];
    const float* Dp     = (const float*)d_in[10];
    const float* W_out  = (const float*)d_in[11];
    float* out = (float*)d_out;

    const size_t R = (size_t)BB * LL;   // 8192 rows

    // ws: xz bf16 64MB | dty bf16 32MB | xdbl f32 3MB | P,S f32 8MB each
    //     | W_x_b (128 rows pad) | W_dt_b | dtr bf16
    bf16*  xz    = (bf16*)d_ws;                    // R * 2*DI
    bf16*  dty   = xz + R * 2 * DI;                // R * DI
    float* xdbl  = (float*)(dty + R * DI);         // R * 96
    float* Pbuf  = xdbl + R * 96;                  // B*NC*DI*DS
    float* Sbuf  = Pbuf + (size_t)BB * NC * DI * DS;
    bf16*  W_x_b  = (bf16*)(Sbuf + (size_t)BB * NC * DI * DS);  // 128*DI (96 used)
    bf16*  W_dt_b = W_x_b + 128 * DI;              // DI * DTR
    bf16*  dtr    = W_dt_b + DI * DTR;             // R * DTR
    const size_t ws_need = (size_t)((char*)(dtr + R * DTR) - (char*)d_ws);
    const bool fast = ws_size >= ws_need;

    bf16*  W_in_b  = dty;   // dead before dt-gemm writes dty
    bf16*  W_out_b = xz;    // converted AFTER scan consumed z

    bf16* xn = (bf16*)d_out;
    bf16* xc = (bf16*)d_out;

    // 0. weight converts
    f2b_kernel<<<(2 * DI * DM / 4) / 256, 256, 0, stream>>>(W_in, W_in_b, 2 * DI * DM / 4);
    if (fast) {
        f2b_kernel<<<(96 * DI / 4 + 255) / 256, 256, 0, stream>>>(W_x, W_x_b, 96 * DI / 4);
        f2b_kernel<<<(DI * DTR / 4 + 255) / 256, 256, 0, stream>>>(W_dt, W_dt_b, DI * DTR / 4);
    }

    // 1. LayerNorm -> xn bf16
    ln_kernel<<<(int)R, 256, 0, stream>>>(x, ln_w, ln_b, xn);

    // 2. in_proj (MFMA): xz[8192,4096] = xn @ W_in^T
    gemm_mfma<0, bf16><<<dim3(2 * DI / 128, R / 128), 256, 0, stream>>>(
        xn, DM, W_in_b, DM, xz, 2 * DI, DM, nullptr);

    // 3. conv + SiLU -> xc
    conv_silu_kernel<<<(int)(R * DI / 4 / 256), 256, 0, stream>>>(
        xz, conv_w, conv_b, xc);

    if (fast) {
        // 4a. x_proj MFMA -> xdbl f32 + dtr bf16
        xproj_mfma<<<(int)(R / 32), 256, 0, stream>>>(xc, W_x_b, xdbl, dtr);
        // 4b. dt = softplus(dtr @ W_dt^T + b_dt) -> dty bf16 (MFMA, K=64)
        gemm_mfma<1, bf16><<<dim3(DI / 128, R / 128), 256, 0, stream>>>(
            dtr, DTR, W_dt_b, DTR, dty, DI, DTR, b_dt);
        // 5. chunked scan
        scan_part1<<<BB * NC * (DI / TCH), 256, 0, stream>>>(
            xdbl, dty, xc, A_log, Pbuf, Sbuf);
        scan_combine<<<BB * DI * DS / 256, 256, 0, stream>>>(Pbuf, Sbuf);
        scan_part2<<<BB * NC * (DI / TCH), 256, 0, stream>>>(
            xdbl, dty, xc, xz, A_log, Dp, Sbuf);
    } else {
        // fallback: f32 small GEMMs + monolithic scan
        gemm_nt<0><<<dim3(2, R / 64), 256, 0, stream>>>(
            xc, DI, W_x, DI, xdbl, 96, (int)R, 96, DI, nullptr);
        gemm_nt<1><<<dim3(DI / 64, R / 64), 256, 0, stream>>>(
            xdbl, 96, W_dt, DTR, dty, DI, (int)R, DI, DTR, b_dt);
        scan_mono<<<BB * (DI / 16), 256, 0, stream>>>(
            xdbl, dty, xc, xz, A_log, Dp);
    }

    // 5b. weight convert (W_out) into xz head (z now dead)
    f2b_kernel<<<(DM * DI / 4) / 256, 256, 0, stream>>>(W_out, W_out_b, DM * DI / 4);

    // 6. out_proj (MFMA) + residual: out = y @ W_out^T + x
    gemm_mfma<2, float><<<dim3(DM / 128, R / 128), 256, 0, stream>>>(
        dty, DI, W_out_b, DI, out, DM, DI, x);
}

// Round 7
// 596.466 us; speedup vs baseline: 3.8794x; 1.1897x over previous
//
#include <hip/hip_runtime.h>
#include <math.h>

#define BB 4
#define LL 2048
#define DM 1024
#define DI 2048
#define DS 16
#define DTR 64
#define NC 16            // scan chunks per sequence
#define CHUNK (LL / NC)  // 128
#define TCH 256          // channels per scan block
#define TT 32            // timesteps per staged tile

typedef unsigned short bf16;
typedef __attribute__((ext_vector_type(8))) short bf16x8;
typedef __attribute__((ext_vector_type(4))) float f32x4;

__device__ inline float b2f(bf16 u) { return __uint_as_float(((unsigned)u) << 16); }
__device__ inline bf16 f2b(float f) {
    unsigned u = __float_as_uint(f);
    u += 0x7FFF + ((u >> 16) & 1);   // round-to-nearest-even
    return (bf16)(u >> 16);
}

__device__ inline float4 ld4(const float* p) { return *(const float4*)p; }
__device__ inline float4 ld4(const bf16* p) {
    ushort4 v = *(const ushort4*)p;
    return make_float4(b2f(v.x), b2f(v.y), b2f(v.z), b2f(v.w));
}
__device__ inline void st1(float* p, float v) { *p = v; }
__device__ inline void st1(bf16* p, float v) { *p = f2b(v); }

// cheap softplus: hw v_exp_f32/v_log_f32 (~8 VALU instrs); bf16-sufficient.
// log1pf is the precise device-lib path (~270 instrs measured via VALUBusy) - never use in epilogues.
__device__ inline float softplus_fast(float v) {
    return (v > 15.f) ? v : __logf(1.f + __expf(v));
}

// async global->LDS, 16 bytes per lane; LDS dest = wave-uniform base + lane*16
__device__ inline void gld_lds16(const void* g, void* l) {
    __builtin_amdgcn_global_load_lds(
        (const __attribute__((address_space(1))) unsigned int*)g,
        (__attribute__((address_space(3))) unsigned int*)l, 16, 0, 0);
}

// ---------------- f32 -> bf16 convert (weights) ------------------------------
__global__ __launch_bounds__(256) void f2b_kernel(const float* __restrict__ in,
    bf16* __restrict__ out, int n4)
{
    int i = blockIdx.x * 256 + threadIdx.x;
    if (i >= n4) return;
    float4 v = *(const float4*)(in + (size_t)i * 4);
    ushort4 o = { f2b(v.x), f2b(v.y), f2b(v.z), f2b(v.w) };
    *(ushort4*)(out + (size_t)i * 4) = o;
}

// ---------------- LayerNorm: one block per row, bf16 out ---------------------
__global__ __launch_bounds__(256) void ln_kernel(const float* __restrict__ x,
    const float* __restrict__ w, const float* __restrict__ b,
    bf16* __restrict__ xn)
{
    int row = blockIdx.x;
    int tid = threadIdx.x;
    const float* xr = x + (size_t)row * DM;
    float4 v = *(const float4*)(xr + tid * 4);
    float s1 = v.x + v.y + v.z + v.w;
    float s2 = v.x * v.x + v.y * v.y + v.z * v.z + v.w * v.w;
    #pragma unroll
    for (int o = 32; o > 0; o >>= 1) {
        s1 += __shfl_xor(s1, o);
        s2 += __shfl_xor(s2, o);
    }
    __shared__ float r1[4], r2[4];
    __shared__ float smu, srs;
    int wv = tid >> 6;
    if ((tid & 63) == 0) { r1[wv] = s1; r2[wv] = s2; }
    __syncthreads();
    if (tid == 0) {
        float t1 = r1[0] + r1[1] + r1[2] + r1[3];
        float t2 = r2[0] + r2[1] + r2[2] + r2[3];
        float mu = t1 * (1.0f / DM);
        float var = t2 * (1.0f / DM) - mu * mu;
        smu = mu;
        srs = rsqrtf(var + 1e-5f);
    }
    __syncthreads();
    float mu = smu, rs = srs;
    float4 wv4 = *(const float4*)(w + tid * 4);
    float4 bv4 = *(const float4*)(b + tid * 4);
    ushort4 o;
    o.x = f2b((v.x - mu) * rs * wv4.x + bv4.x);
    o.y = f2b((v.y - mu) * rs * wv4.y + bv4.y);
    o.z = f2b((v.z - mu) * rs * wv4.z + bv4.z);
    o.w = f2b((v.w - mu) * rs * wv4.w + bv4.w);
    *(ushort4*)(xn + (size_t)row * DM + tid * 4) = o;
}

// ---------------- MFMA bf16 GEMM, NT: C[m,n] = sum_k A[m,k]*B[n,k] ----------
// 128x128 tile, BK=32. EPI 0: plain. EPI 1: softplus(acc+aux[n]).
// EPI 2: acc + aux[m*ldc+n].
template<int EPI, typename TC>
__global__ __launch_bounds__(256) void gemm_mfma(
    const bf16* __restrict__ A, int lda,
    const bf16* __restrict__ B, int ldb,
    TC* __restrict__ C, int ldc,
    int K, const float* __restrict__ aux)
{
    __shared__ bf16 As[128 * 32];
    __shared__ bf16 Bs[128 * 32];
    const int tid = threadIdx.x;
    const int lane = tid & 63;
    const int w = tid >> 6;
    const int wm = w >> 1, wn = w & 1;
    const int m0 = blockIdx.y * 128, n0 = blockIdx.x * 128;

    const int srow = lane >> 2;
    const int schunk = (lane & 3) * 8;

    const int fm = lane & 15;
    const int fq = lane >> 4;

    f32x4 acc[4][4] = {};

    for (int kt = 0; kt < K; kt += 32) {
        #pragma unroll
        for (int i = 0; i < 2; i++) {
            int r0 = i * 64 + w * 16;
            gld_lds16(A + (size_t)(m0 + r0 + srow) * lda + kt + schunk, &As[r0 * 32]);
            gld_lds16(B + (size_t)(n0 + r0 + srow) * ldb + kt + schunk, &Bs[r0 * 32]);
        }
        __syncthreads();
        bf16x8 af[4], bfr[4];
        #pragma unroll
        for (int i = 0; i < 4; i++) {
            af[i]  = *(const bf16x8*)&As[(wm * 64 + i * 16 + fm) * 32 + fq * 8];
            bfr[i] = *(const bf16x8*)&Bs[(wn * 64 + i * 16 + fm) * 32 + fq * 8];
        }
        #pragma unroll
        for (int i = 0; i < 4; i++)
            #pragma unroll
            for (int j = 0; j < 4; j++)
                acc[i][j] = __builtin_amdgcn_mfma_f32_16x16x32_bf16(
                    af[i], bfr[j], acc[i][j], 0, 0, 0);
        __syncthreads();
    }

    #pragma unroll
    for (int i = 0; i < 4; i++) {
        #pragma unroll
        for (int r = 0; r < 4; r++) {
            int m = m0 + wm * 64 + i * 16 + fq * 4 + r;
            #pragma unroll
            for (int j = 0; j < 4; j++) {
                int n = n0 + wn * 64 + j * 16 + fm;
                float v = acc[i][j][r];
                if (EPI == 1) {
                    v = softplus_fast(v + aux[n]);
                } else if (EPI == 2) {
                    v += aux[(size_t)m * ldc + n];
                }
                st1(&C[(size_t)m * ldc + n], v);
            }
        }
    }
}

// ---------------- x_proj MFMA: xdbl[R,96] = xc[R,DI] @ W_x[96,DI]^T ----------
// 32-row M tile (grid R/32 = 256), waves 2m x 2n, each 16 rows x 48 cols.
// Also emits bf16 copy of cols 0..63 (dt_r) for the dt GEMM.
__global__ __launch_bounds__(256) void xproj_mfma(
    const bf16* __restrict__ A,      // xc [R, DI]
    const bf16* __restrict__ Bm,     // W_x bf16, padded to 128 rows [128, DI]
    float* __restrict__ Cx,          // xdbl [R, 96]
    bf16* __restrict__ dtr)          // [R, 64]
{
    __shared__ bf16 As[32 * 32];
    __shared__ bf16 Bs[128 * 32];
    const int tid = threadIdx.x;
    const int lane = tid & 63;
    const int w = tid >> 6;
    const int wm = w >> 1, wn = w & 1;
    const int m0 = blockIdx.x * 32;
    const int srow = lane >> 2;
    const int schunk = (lane & 3) * 8;
    const int fm = lane & 15;
    const int fq = lane >> 4;
    f32x4 acc[3] = {};
    for (int kt = 0; kt < DI; kt += 32) {
        if (w < 2) {
            int r0 = w * 16;
            gld_lds16(A + (size_t)(m0 + r0 + srow) * DI + kt + schunk, &As[r0 * 32]);
        }
        {
            int r0 = w * 32;
            gld_lds16(Bm + (size_t)(r0 + srow) * DI + kt + schunk, &Bs[r0 * 32]);
            gld_lds16(Bm + (size_t)(r0 + 16 + srow) * DI + kt + schunk, &Bs[(r0 + 16) * 32]);
        }
        __syncthreads();
        bf16x8 af = *(const bf16x8*)&As[(wm * 16 + fm) * 32 + fq * 8];
        #pragma unroll
        for (int j = 0; j < 3; j++) {
            bf16x8 bf = *(const bf16x8*)&Bs[((wn * 3 + j) * 16 + fm) * 32 + fq * 8];
            acc[j] = __builtin_amdgcn_mfma_f32_16x16x32_bf16(af, bf, acc[j], 0, 0, 0);
        }
        __syncthreads();
    }
    #pragma unroll
    for (int j = 0; j < 3; j++) {
        int col = (wn * 3 + j) * 16 + fm;
        #pragma unroll
        for (int r = 0; r < 4; r++) {
            int m = m0 + wm * 16 + fq * 4 + r;
            float v = acc[j][r];
            Cx[(size_t)m * 96 + col] = v;
            if (col < 64) dtr[(size_t)m * 64 + col] = f2b(v);
        }
    }
}

// ---------------- Tiled f32-compute GEMM (fallback path only) ----------------
template<int EPI, typename TA, typename TB, typename TC>
__global__ __launch_bounds__(256) void gemm_nt(
    const TA* __restrict__ A, int lda,
    const TB* __restrict__ B, int ldb,
    TC* __restrict__ C, int ldc,
    int M, int N, int K,
    const float* __restrict__ aux)
{
    __shared__ float As[16][64];
    __shared__ float Bs[16][64];
    int tid = threadIdx.x;
    int m0 = blockIdx.y * 64, n0 = blockIdx.x * 64;
    int lr = tid >> 2;
    int lc = (tid & 3) * 4;
    int tm = tid >> 4;
    int tn = tid & 15;
    float acc[4][4] = {};
    for (int kt = 0; kt < K; kt += 16) {
        float4 av = ld4(A + (size_t)(m0 + lr) * lda + kt + lc);
        float4 bv = make_float4(0.f, 0.f, 0.f, 0.f);
        if (n0 + lr < N)
            bv = ld4(B + (size_t)(n0 + lr) * ldb + kt + lc);
        As[lc + 0][lr] = av.x; As[lc + 1][lr] = av.y;
        As[lc + 2][lr] = av.z; As[lc + 3][lr] = av.w;
        Bs[lc + 0][lr] = bv.x; Bs[lc + 1][lr] = bv.y;
        Bs[lc + 2][lr] = bv.z; Bs[lc + 3][lr] = bv.w;
        __syncthreads();
        #pragma unroll
        for (int k = 0; k < 16; k++) {
            float4 a4 = *(const float4*)&As[k][tm * 4];
            float4 b4 = *(const float4*)&Bs[k][tn * 4];
            float am[4] = {a4.x, a4.y, a4.z, a4.w};
            float bn[4] = {b4.x, b4.y, b4.z, b4.w};
            #pragma unroll
            for (int i = 0; i < 4; i++)
                #pragma unroll
                for (int j = 0; j < 4; j++)
                    acc[i][j] = fmaf(am[i], bn[j], acc[i][j]);
        }
        __syncthreads();
    }
    #pragma unroll
    for (int i = 0; i < 4; i++) {
        int m = m0 + tm * 4 + i;
        #pragma unroll
        for (int j = 0; j < 4; j++) {
            int n = n0 + tn * 4 + j;
            if (n >= N) continue;
            float v = acc[i][j];
            if (EPI == 1) {
                v = softplus_fast(v + aux[n]);
            }
            st1(&C[(size_t)m * ldc + n], v);
        }
    }
}

// ---------------- Depthwise causal conv (4 taps) + SiLU ----------------------
__global__ __launch_bounds__(256) void conv_silu_kernel(
    const bf16* __restrict__ xz, const float* __restrict__ cw,
    const float* __restrict__ cb, bf16* __restrict__ xc)
{
    int idx = blockIdx.x * 256 + threadIdx.x;
    int d4 = idx & (DI / 4 - 1);
    int bl = idx >> 9;
    int l = bl & (LL - 1);
    int d0 = d4 * 4;
    float4 bias = *(const float4*)(cb + d0);
    float acc[4] = {bias.x, bias.y, bias.z, bias.w};
    #pragma unroll
    for (int k = 0; k < 4; k++) {
        int lp = l - 3 + k;
        if (lp < 0) continue;
        float4 xv = ld4(xz + (size_t)(bl - 3 + k) * (2 * DI) + d0);
        acc[0] = fmaf(xv.x, cw[(d0 + 0) * 4 + k], acc[0]);
        acc[1] = fmaf(xv.y, cw[(d0 + 1) * 4 + k], acc[1]);
        acc[2] = fmaf(xv.z, cw[(d0 + 2) * 4 + k], acc[2]);
        acc[3] = fmaf(xv.w, cw[(d0 + 3) * 4 + k], acc[3]);
    }
    ushort4 o;
    o.x = f2b(acc[0] / (1.f + __expf(-acc[0])));
    o.y = f2b(acc[1] / (1.f + __expf(-acc[1])));
    o.z = f2b(acc[2] / (1.f + __expf(-acc[2])));
    o.w = f2b(acc[3] / (1.f + __expf(-acc[3])));
    *(ushort4*)(xc + (size_t)bl * DI + d0) = o;
}

// ---------------- Chunked selective scan, thread-per-channel -----------------
__global__ __launch_bounds__(256) void scan_part1(
    const float* __restrict__ xdbl, const bf16* __restrict__ dty,
    const bf16* __restrict__ xc, const float* __restrict__ A_log,
    float* __restrict__ P, float* __restrict__ S)
{
    __shared__ bf16 sdt[TT][TCH];
    __shared__ bf16 su[TT][TCH];
    __shared__ alignas(16) float sBC[TT][32];
    int bid = blockIdx.x;
    int cg = bid & 7;                 // DI/TCH = 8
    int c  = (bid >> 3) & (NC - 1);
    int b  = bid >> 7;
    int d0 = cg * TCH;
    int tid = threadIdx.x;
    int w = tid >> 6, l = tid & 63;
    int lrow = l >> 5, lcol = (l & 31) * 8;
    int brow = l >> 3, bcol = (l & 7) * 4;
    int d = d0 + tid;

    float Ads[16];
    #pragma unroll
    for (int q = 0; q < 4; q++) {
        float4 a4 = *(const float4*)&A_log[(size_t)d * DS + q * 4];
        Ads[q*4+0] = -__expf(a4.x); Ads[q*4+1] = -__expf(a4.y);
        Ads[q*4+2] = -__expf(a4.z); Ads[q*4+3] = -__expf(a4.w);
    }
    float h[16], p[16];
    #pragma unroll
    for (int s = 0; s < 16; s++) { h[s] = 0.f; p[s] = 1.f; }

    const size_t rowbase = (size_t)b * LL + c * CHUNK;
    for (int t0 = 0; t0 < CHUNK; t0 += TT) {
        #pragma unroll
        for (int pp = 0; pp < 4; pp++) {
            int r0 = (pp * 4 + w) * 2;
            size_t grow = rowbase + t0 + r0 + lrow;
            gld_lds16(dty + grow * DI + d0 + lcol, &sdt[r0][0]);
            gld_lds16(xc  + grow * DI + d0 + lcol, &su[r0][0]);
        }
        gld_lds16(xdbl + (rowbase + t0 + w * 8 + brow) * 96 + DTR + bcol,
                  &sBC[w * 8][0]);
        __syncthreads();
        for (int t = 0; t < TT; t++) {
            float dtv = b2f(sdt[t][tid]);
            float uv  = b2f(su[t][tid]);
            float tmp = dtv * uv;
            const float4* bc = (const float4*)&sBC[t][0];
            float4 B0 = bc[0], B1 = bc[1], B2 = bc[2], B3 = bc[3];
            float Bv[16] = {B0.x,B0.y,B0.z,B0.w, B1.x,B1.y,B1.z,B1.w,
                            B2.x,B2.y,B2.z,B2.w, B3.x,B3.y,B3.z,B3.w};
            #pragma unroll
            for (int s = 0; s < 16; s++) {
                float dA = __expf(dtv * Ads[s]);
                h[s] = dA * h[s] + tmp * Bv[s];
                p[s] *= dA;
            }
        }
        __syncthreads();
    }
    size_t o = ((size_t)(b * NC + c) * DI + d) * DS;
    #pragma unroll
    for (int q = 0; q < 4; q++) {
        *(float4*)&P[o + q*4] = make_float4(p[q*4], p[q*4+1], p[q*4+2], p[q*4+3]);
        *(float4*)&S[o + q*4] = make_float4(h[q*4], h[q*4+1], h[q*4+2], h[q*4+3]);
    }
}

__global__ __launch_bounds__(256) void scan_combine(
    const float* __restrict__ P, float* __restrict__ S)
{
    int g = blockIdx.x * 256 + threadIdx.x;   // B*DI*DS threads
    int b = g >> 15;                          // DI*DS = 32768
    int rem = g & 32767;
    float h = 0.f;
    #pragma unroll
    for (int c = 0; c < NC; c++) {
        size_t o = ((size_t)(b * NC + c) << 15) + rem;
        float p = P[o], sv = S[o];
        S[o] = h;                             // h_in for chunk c
        h = p * h + sv;
    }
}

__global__ __launch_bounds__(256) void scan_part2(
    const float* __restrict__ xdbl, bf16* __restrict__ dty,
    const bf16* __restrict__ xc, const bf16* __restrict__ xz,
    const float* __restrict__ A_log, const float* __restrict__ Dp,
    const float* __restrict__ Hin)
{
    __shared__ bf16 sdt[TT][TCH];
    __shared__ bf16 su[TT][TCH];
    __shared__ bf16 sz[TT][TCH];
    __shared__ alignas(16) float sBC[TT][32];
    int bid = blockIdx.x;
    int cg = bid & 7;
    int c  = (bid >> 3) & (NC - 1);
    int b  = bid >> 7;
    int d0 = cg * TCH;
    int tid = threadIdx.x;
    int w = tid >> 6, l = tid & 63;
    int lrow = l >> 5, lcol = (l & 31) * 8;
    int brow = l >> 3, bcol = (l & 7) * 4;
    int d = d0 + tid;

    float Ads[16];
    #pragma unroll
    for (int q = 0; q < 4; q++) {
        float4 a4 = *(const float4*)&A_log[(size_t)d * DS + q * 4];
        Ads[q*4+0] = -__expf(a4.x); Ads[q*4+1] = -__expf(a4.y);
        Ads[q*4+2] = -__expf(a4.z); Ads[q*4+3] = -__expf(a4.w);
    }
    float h[16];
    size_t ho = ((size_t)(b * NC + c) * DI + d) * DS;
    #pragma unroll
    for (int q = 0; q < 4; q++) {
        float4 hv = *(const float4*)&Hin[ho + q*4];
        h[q*4] = hv.x; h[q*4+1] = hv.y; h[q*4+2] = hv.z; h[q*4+3] = hv.w;
    }
    float dpd = Dp[d];

    const size_t rowbase = (size_t)b * LL + c * CHUNK;
    for (int t0 = 0; t0 < CHUNK; t0 += TT) {
        #pragma unroll
        for (int pp = 0; pp < 4; pp++) {
            int r0 = (pp * 4 + w) * 2;
            size_t grow = rowbase + t0 + r0 + lrow;
            gld_lds16(dty + grow * DI + d0 + lcol, &sdt[r0][0]);
            gld_lds16(xc  + grow * DI + d0 + lcol, &su[r0][0]);
            gld_lds16(xz  + grow * (2 * DI) + DI + d0 + lcol, &sz[r0][0]);
        }
        gld_lds16(xdbl + (rowbase + t0 + w * 8 + brow) * 96 + DTR + bcol,
                  &sBC[w * 8][0]);
        __syncthreads();
        for (int t = 0; t < TT; t++) {
            float dtv = b2f(sdt[t][tid]);
            float uv  = b2f(su[t][tid]);
            float tmp = dtv * uv;
            const float4* bc = (const float4*)&sBC[t][0];
            float4 B0 = bc[0], B1 = bc[1], B2 = bc[2], B3 = bc[3];
            float4 C0 = bc[4], C1 = bc[5], C2 = bc[6], C3 = bc[7];
            float Bv[16] = {B0.x,B0.y,B0.z,B0.w, B1.x,B1.y,B1.z,B1.w,
                            B2.x,B2.y,B2.z,B2.w, B3.x,B3.y,B3.z,B3.w};
            float Cv[16] = {C0.x,C0.y,C0.z,C0.w, C1.x,C1.y,C1.z,C1.w,
                            C2.x,C2.y,C2.z,C2.w, C3.x,C3.y,C3.z,C3.w};
            float y = 0.f;
            #pragma unroll
            for (int s = 0; s < 16; s++) {
                float dA = __expf(dtv * Ads[s]);
                h[s] = dA * h[s] + tmp * Bv[s];
                y = fmaf(h[s], Cv[s], y);
            }
            float zv = b2f(sz[t][tid]);
            float yo = (y + uv * dpd) * (zv / (1.f + __expf(-zv)));
            dty[(rowbase + t0 + t) * DI + d] = f2b(yo);
        }
        __syncthreads();
    }
}

// ---------------- Monolithic scan (fallback when ws is small) ----------------
__global__ __launch_bounds__(256) void scan_mono(
    const float* __restrict__ xdbl, bf16* __restrict__ dty,
    const bf16* __restrict__ xc, const bf16* __restrict__ xz,
    const float* __restrict__ A_log, const float* __restrict__ Dp)
{
    const int TC = 64;
    int b = blockIdx.x >> 7;
    int dblk = blockIdx.x & 127;
    int d0 = dblk * 16;
    int tid = threadIdx.x;
    int s = tid & 15;
    int dg = tid >> 4;
    int d = d0 + dg;
    float Ads = -__expf(A_log[(size_t)d * DS + s]);
    float h = 0.f;
    __shared__ float sdt[TC][16], su[TC][16], sB[TC][16], sC[TC][16], sy[TC][16];
    const size_t rowbase = (size_t)b * LL;
    int wi = tid >> 2;
    int wj = (tid & 3) * 4;
    float4 dpv = *(const float4*)(Dp + d0 + wj);
    for (int t0 = 0; t0 < LL; t0 += TC) {
        {
            size_t g = (rowbase + t0 + wi) * (size_t)DI + d0 + wj;
            *(float4*)&sdt[wi][wj] = ld4(dty + g);
            *(float4*)&su[wi][wj]  = ld4(xc + g);
        }
        #pragma unroll
        for (int r = 0; r < 4; r++) {
            int i = (tid >> 4) + r * 16;
            size_t g = (rowbase + t0 + i) * 96;
            sB[i][s] = xdbl[g + DTR + s];
            sC[i][s] = xdbl[g + DTR + DS + s];
        }
        __syncthreads();
        for (int i = 0; i < TC; i++) {
            float dtv = sdt[i][dg];
            float dA = __expf(dtv * Ads);
            h = dA * h + dtv * su[i][dg] * sB[i][s];
            float yp = h * sC[i][s];
            yp += __shfl_xor(yp, 1);
            yp += __shfl_xor(yp, 2);
            yp += __shfl_xor(yp, 4);
            yp += __shfl_xor(yp, 8);
            if (s == 0) sy[i][dg] = yp;
        }
        __syncthreads();
        {
            size_t g  = (rowbase + t0 + wi) * (size_t)DI + d0 + wj;
            size_t gz = (rowbase + t0 + wi) * (size_t)(2 * DI) + DI + d0 + wj;
            float4 zv = ld4(xz + gz);
            float4 yv = *(const float4*)&sy[wi][wj];
            float4 uv = *(const float4*)&su[wi][wj];
            ushort4 o;
            o.x = f2b((yv.x + uv.x * dpv.x) * (zv.x / (1.f + __expf(-zv.x))));
            o.y = f2b((yv.y + uv.y * dpv.y) * (zv.y / (1.f + __expf(-zv.y))));
            o.z = f2b((yv.z + uv.z * dpv.z) * (zv.z / (1.f + __expf(-zv.z))));
            o.w = f2b((yv.w + uv.w * dpv.w) * (zv.w / (1.f + __expf(-zv.w))));
            *(ushort4*)(dty + g) = o;
        }
        __syncthreads();
    }
}

// ---------------------------------------------------------------------------
extern "C" void kernel_launch(void* const* d_in, const int* in_sizes, int n_in,
                              void* d_out, int out_size, void* d_ws, size_t ws_size,
                              hipStream_t stream)
{
    const float* x      = (const float*)d_in[0];
    const float* ln_w   = (const float*)d_in[1];
    const float* ln_b   = (const float*)d_in[2];
    const float* W_in   = (const float*)d_in[3];
    const float* conv_w = (const float*)d_in[4];
    const float* conv_b = (const float*)d_in[5];
    const float* W_x    = (const float*)d_in[6];
    const float* W_dt   = (const float*)d_in[7];
    const float* b_dt   = (const float*)d_in[8];
    const float* A_log  = (const float*)d_in[9];
    const float* Dp     = (const float*)d_in[10];
    const float* W_out  = (const float*)d_in[11];
    float* out = (float*)d_out;

    const size_t R = (size_t)BB * LL;   // 8192 rows

    // ws: xz bf16 64MB | dty bf16 32MB | xdbl f32 3MB | P,S f32 8MB each
    //     | W_x_b (128 rows pad) | W_dt_b | dtr bf16
    bf16*  xz    = (bf16*)d_ws;                    // R * 2*DI
    bf16*  dty   = xz + R * 2 * DI;                // R * DI
    float* xdbl  = (float*)(dty + R * DI);         // R * 96
    float* Pbuf  = xdbl + R * 96;                  // B*NC*DI*DS
    float* Sbuf  = Pbuf + (size_t)BB * NC * DI * DS;
    bf16*  W_x_b  = (bf16*)(Sbuf + (size_t)BB * NC * DI * DS);  // 128*DI (96 used)
    bf16*  W_dt_b = W_x_b + 128 * DI;              // DI * DTR
    bf16*  dtr    = W_dt_b + DI * DTR;             // R * DTR
    const size_t ws_need = (size_t)((char*)(dtr + R * DTR) - (char*)d_ws);
    const bool fast = ws_size >= ws_need;

    bf16*  W_in_b  = dty;   // dead before dt-gemm writes dty
    bf16*  W_out_b = xz;    // converted AFTER scan consumed z

    bf16* xn = (bf16*)d_out;
    bf16* xc = (bf16*)d_out;

    // 0. weight converts
    f2b_kernel<<<(2 * DI * DM / 4) / 256, 256, 0, stream>>>(W_in, W_in_b, 2 * DI * DM / 4);
    if (fast) {
        f2b_kernel<<<(96 * DI / 4 + 255) / 256, 256, 0, stream>>>(W_x, W_x_b, 96 * DI / 4);
        f2b_kernel<<<(DI * DTR / 4 + 255) / 256, 256, 0, stream>>>(W_dt, W_dt_b, DI * DTR / 4);
    }

    // 1. LayerNorm -> xn bf16
    ln_kernel<<<(int)R, 256, 0, stream>>>(x, ln_w, ln_b, xn);

    // 2. in_proj (MFMA): xz[8192,4096] = xn @ W_in^T
    gemm_mfma<0, bf16><<<dim3(2 * DI / 128, R / 128), 256, 0, stream>>>(
        xn, DM, W_in_b, DM, xz, 2 * DI, DM, nullptr);

    // 3. conv + SiLU -> xc
    conv_silu_kernel<<<(int)(R * DI / 4 / 256), 256, 0, stream>>>(
        xz, conv_w, conv_b, xc);

    if (fast) {
        // 4a. x_proj MFMA -> xdbl f32 + dtr bf16
        xproj_mfma<<<(int)(R / 32), 256, 0, stream>>>(xc, W_x_b, xdbl, dtr);
        // 4b. dt = softplus(dtr @ W_dt^T + b_dt) -> dty bf16 (MFMA, K=64)
        gemm_mfma<1, bf16><<<dim3(DI / 128, R / 128), 256, 0, stream>>>(
            dtr, DTR, W_dt_b, DTR, dty, DI, DTR, b_dt);
        // 5. chunked scan
        scan_part1<<<BB * NC * (DI / TCH), 256, 0, stream>>>(
            xdbl, dty, xc, A_log, Pbuf, Sbuf);
        scan_combine<<<BB * DI * DS / 256, 256, 0, stream>>>(Pbuf, Sbuf);
        scan_part2<<<BB * NC * (DI / TCH), 256, 0, stream>>>(
            xdbl, dty, xc, xz, A_log, Dp, Sbuf);
    } else {
        // fallback: f32 small GEMMs + monolithic scan
        gemm_nt<0><<<dim3(2, R / 64), 256, 0, stream>>>(
            xc, DI, W_x, DI, xdbl, 96, (int)R, 96, DI, nullptr);
        gemm_nt<1><<<dim3(DI / 64, R / 64), 256, 0, stream>>>(
            xdbl, 96, W_dt, DTR, dty, DI, (int)R, DI, DTR, b_dt);
        scan_mono<<<BB * (DI / 16), 256, 0, stream>>>(
            xdbl, dty, xc, xz, A_log, Dp);
    }

    // 5b. weight convert (W_out) into xz head (z now dead)
    f2b_kernel<<<(DM * DI / 4) / 256, 256, 0, stream>>>(W_out, W_out_b, DM * DI / 4);

    // 6. out_proj (MFMA) + residual: out = y @ W_out^T + x
    gemm_mfma<2, float><<<dim3(DM / 128, R / 128), 256, 0, stream>>>(
        dty, DI, W_out_b, DI, out, DM, DI, x);
}

// Round 8
// 498.219 us; speedup vs baseline: 4.6444x; 1.1972x over previous
//
#include <hip/hip_runtime.h>
#include <math.h>

#define BB 4
#define LL 2048
#define DM 1024
#define DI 2048
#define DS 16
#define DTR 64
#define NC 16            // scan chunks per sequence
#define CHUNK (LL / NC)  // 128
#define TCH 256          // channels per scan block
#define TT 32            // timesteps per staged tile

typedef unsigned short bf16;
typedef __attribute__((ext_vector_type(8))) short bf16x8;
typedef __attribute__((ext_vector_type(4))) float f32x4;

__device__ inline float b2f(bf16 u) { return __uint_as_float(((unsigned)u) << 16); }
__device__ inline bf16 f2b(float f) {
    unsigned u = __float_as_uint(f);
    u += 0x7FFF + ((u >> 16) & 1);   // round-to-nearest-even
    return (bf16)(u >> 16);
}

__device__ inline float4 ld4(const float* p) { return *(const float4*)p; }
__device__ inline float4 ld4(const bf16* p) {
    ushort4 v = *(const ushort4*)p;
    return make_float4(b2f(v.x), b2f(v.y), b2f(v.z), b2f(v.w));
}
__device__ inline void st1(float* p, float v) { *p = v; }
__device__ inline void st1(bf16* p, float v) { *p = f2b(v); }

// cheap softplus: hw v_exp_f32/v_log_f32 (~8 VALU instrs); bf16-sufficient.
// log1pf is the precise device-lib path (~270 instrs measured via VALUBusy) - never use in epilogues.
__device__ inline float softplus_fast(float v) {
    return (v > 15.f) ? v : __logf(1.f + __expf(v));
}

// async global->LDS, 16 bytes per lane; LDS dest = wave-uniform base + lane*16
__device__ inline void gld_lds16(const void* g, void* l) {
    __builtin_amdgcn_global_load_lds(
        (const __attribute__((address_space(1))) unsigned int*)g,
        (__attribute__((address_space(3))) unsigned int*)l, 16, 0, 0);
}

// ---------------- f32 -> bf16 convert (weights) ------------------------------
__global__ __launch_bounds__(256) void f2b_kernel(const float* __restrict__ in,
    bf16* __restrict__ out, int n4)
{
    int i = blockIdx.x * 256 + threadIdx.x;
    if (i >= n4) return;
    float4 v = *(const float4*)(in + (size_t)i * 4);
    ushort4 o = { f2b(v.x), f2b(v.y), f2b(v.z), f2b(v.w) };
    *(ushort4*)(out + (size_t)i * 4) = o;
}

// ---------------- conv weight transpose: [DI][4] f32 -> [4][DI] bf16 ---------
__global__ __launch_bounds__(256) void convw_transpose(
    const float* __restrict__ cw, bf16* __restrict__ cwt)
{
    int d = blockIdx.x * 256 + threadIdx.x;
    if (d >= DI) return;
    float4 w = *(const float4*)(cw + d * 4);
    cwt[0 * DI + d] = f2b(w.x);
    cwt[1 * DI + d] = f2b(w.y);
    cwt[2 * DI + d] = f2b(w.z);
    cwt[3 * DI + d] = f2b(w.w);
}

// ---------------- LayerNorm: one block per row, bf16 out ---------------------
__global__ __launch_bounds__(256) void ln_kernel(const float* __restrict__ x,
    const float* __restrict__ w, const float* __restrict__ b,
    bf16* __restrict__ xn)
{
    int row = blockIdx.x;
    int tid = threadIdx.x;
    const float* xr = x + (size_t)row * DM;
    float4 v = *(const float4*)(xr + tid * 4);
    float s1 = v.x + v.y + v.z + v.w;
    float s2 = v.x * v.x + v.y * v.y + v.z * v.z + v.w * v.w;
    #pragma unroll
    for (int o = 32; o > 0; o >>= 1) {
        s1 += __shfl_xor(s1, o);
        s2 += __shfl_xor(s2, o);
    }
    __shared__ float r1[4], r2[4];
    __shared__ float smu, srs;
    int wv = tid >> 6;
    if ((tid & 63) == 0) { r1[wv] = s1; r2[wv] = s2; }
    __syncthreads();
    if (tid == 0) {
        float t1 = r1[0] + r1[1] + r1[2] + r1[3];
        float t2 = r2[0] + r2[1] + r2[2] + r2[3];
        float mu = t1 * (1.0f / DM);
        float var = t2 * (1.0f / DM) - mu * mu;
        smu = mu;
        srs = rsqrtf(var + 1e-5f);
    }
    __syncthreads();
    float mu = smu, rs = srs;
    float4 wv4 = *(const float4*)(w + tid * 4);
    float4 bv4 = *(const float4*)(b + tid * 4);
    ushort4 o;
    o.x = f2b((v.x - mu) * rs * wv4.x + bv4.x);
    o.y = f2b((v.y - mu) * rs * wv4.y + bv4.y);
    o.z = f2b((v.z - mu) * rs * wv4.z + bv4.z);
    o.w = f2b((v.w - mu) * rs * wv4.w + bv4.w);
    *(ushort4*)(xn + (size_t)row * DM + tid * 4) = o;
}

// ---------------- MFMA bf16 GEMM, NT: C[m,n] = sum_k A[m,k]*B[n,k] ----------
// 128x128 tile, BK=32. EPI 0: plain. EPI 1: softplus(acc+aux[n]).
// EPI 2: acc + aux[m*ldc+n].
template<int EPI, typename TC>
__global__ __launch_bounds__(256) void gemm_mfma(
    const bf16* __restrict__ A, int lda,
    const bf16* __restrict__ B, int ldb,
    TC* __restrict__ C, int ldc,
    int K, const float* __restrict__ aux)
{
    __shared__ bf16 As[128 * 32];
    __shared__ bf16 Bs[128 * 32];
    const int tid = threadIdx.x;
    const int lane = tid & 63;
    const int w = tid >> 6;
    const int wm = w >> 1, wn = w & 1;
    const int m0 = blockIdx.y * 128, n0 = blockIdx.x * 128;

    const int srow = lane >> 2;
    const int schunk = (lane & 3) * 8;

    const int fm = lane & 15;
    const int fq = lane >> 4;

    f32x4 acc[4][4] = {};

    for (int kt = 0; kt < K; kt += 32) {
        #pragma unroll
        for (int i = 0; i < 2; i++) {
            int r0 = i * 64 + w * 16;
            gld_lds16(A + (size_t)(m0 + r0 + srow) * lda + kt + schunk, &As[r0 * 32]);
            gld_lds16(B + (size_t)(n0 + r0 + srow) * ldb + kt + schunk, &Bs[r0 * 32]);
        }
        __syncthreads();
        bf16x8 af[4], bfr[4];
        #pragma unroll
        for (int i = 0; i < 4; i++) {
            af[i]  = *(const bf16x8*)&As[(wm * 64 + i * 16 + fm) * 32 + fq * 8];
            bfr[i] = *(const bf16x8*)&Bs[(wn * 64 + i * 16 + fm) * 32 + fq * 8];
        }
        #pragma unroll
        for (int i = 0; i < 4; i++)
            #pragma unroll
            for (int j = 0; j < 4; j++)
                acc[i][j] = __builtin_amdgcn_mfma_f32_16x16x32_bf16(
                    af[i], bfr[j], acc[i][j], 0, 0, 0);
        __syncthreads();
    }

    #pragma unroll
    for (int i = 0; i < 4; i++) {
        #pragma unroll
        for (int r = 0; r < 4; r++) {
            int m = m0 + wm * 64 + i * 16 + fq * 4 + r;
            #pragma unroll
            for (int j = 0; j < 4; j++) {
                int n = n0 + wn * 64 + j * 16 + fm;
                float v = acc[i][j][r];
                if (EPI == 1) {
                    v = softplus_fast(v + aux[n]);
                } else if (EPI == 2) {
                    v += aux[(size_t)m * ldc + n];
                }
                st1(&C[(size_t)m * ldc + n], v);
            }
        }
    }
}

// ---------------- x_proj MFMA: xdbl[R,96] = xc[R,DI] @ W_x[96,DI]^T ----------
// 32-row M tile (grid R/32 = 256), waves 2m x 2n, each 16 rows x 48 cols.
// Also emits bf16 copy of cols 0..63 (dt_r) for the dt GEMM.
__global__ __launch_bounds__(256) void xproj_mfma(
    const bf16* __restrict__ A,      // xc [R, DI]
    const bf16* __restrict__ Bm,     // W_x bf16, padded to 128 rows [128, DI]
    float* __restrict__ Cx,          // xdbl [R, 96]
    bf16* __restrict__ dtr)          // [R, 64]
{
    __shared__ bf16 As[32 * 32];
    __shared__ bf16 Bs[128 * 32];
    const int tid = threadIdx.x;
    const int lane = tid & 63;
    const int w = tid >> 6;
    const int wm = w >> 1, wn = w & 1;
    const int m0 = blockIdx.x * 32;
    const int srow = lane >> 2;
    const int schunk = (lane & 3) * 8;
    const int fm = lane & 15;
    const int fq = lane >> 4;
    f32x4 acc[3] = {};
    for (int kt = 0; kt < DI; kt += 32) {
        if (w < 2) {
            int r0 = w * 16;
            gld_lds16(A + (size_t)(m0 + r0 + srow) * DI + kt + schunk, &As[r0 * 32]);
        }
        {
            int r0 = w * 32;
            gld_lds16(Bm + (size_t)(r0 + srow) * DI + kt + schunk, &Bs[r0 * 32]);
            gld_lds16(Bm + (size_t)(r0 + 16 + srow) * DI + kt + schunk, &Bs[(r0 + 16) * 32]);
        }
        __syncthreads();
        bf16x8 af = *(const bf16x8*)&As[(wm * 16 + fm) * 32 + fq * 8];
        #pragma unroll
        for (int j = 0; j < 3; j++) {
            bf16x8 bf = *(const bf16x8*)&Bs[((wn * 3 + j) * 16 + fm) * 32 + fq * 8];
            acc[j] = __builtin_amdgcn_mfma_f32_16x16x32_bf16(af, bf, acc[j], 0, 0, 0);
        }
        __syncthreads();
    }
    #pragma unroll
    for (int j = 0; j < 3; j++) {
        int col = (wn * 3 + j) * 16 + fm;
        #pragma unroll
        for (int r = 0; r < 4; r++) {
            int m = m0 + wm * 16 + fq * 4 + r;
            float v = acc[j][r];
            Cx[(size_t)m * 96 + col] = v;
            if (col < 64) dtr[(size_t)m * 64 + col] = f2b(v);
        }
    }
}

// ---------------- Tiled f32-compute GEMM (fallback path only) ----------------
template<int EPI, typename TA, typename TB, typename TC>
__global__ __launch_bounds__(256) void gemm_nt(
    const TA* __restrict__ A, int lda,
    const TB* __restrict__ B, int ldb,
    TC* __restrict__ C, int ldc,
    int M, int N, int K,
    const float* __restrict__ aux)
{
    __shared__ float As[16][64];
    __shared__ float Bs[16][64];
    int tid = threadIdx.x;
    int m0 = blockIdx.y * 64, n0 = blockIdx.x * 64;
    int lr = tid >> 2;
    int lc = (tid & 3) * 4;
    int tm = tid >> 4;
    int tn = tid & 15;
    float acc[4][4] = {};
    for (int kt = 0; kt < K; kt += 16) {
        float4 av = ld4(A + (size_t)(m0 + lr) * lda + kt + lc);
        float4 bv = make_float4(0.f, 0.f, 0.f, 0.f);
        if (n0 + lr < N)
            bv = ld4(B + (size_t)(n0 + lr) * ldb + kt + lc);
        As[lc + 0][lr] = av.x; As[lc + 1][lr] = av.y;
        As[lc + 2][lr] = av.z; As[lc + 3][lr] = av.w;
        Bs[lc + 0][lr] = bv.x; Bs[lc + 1][lr] = bv.y;
        Bs[lc + 2][lr] = bv.z; Bs[lc + 3][lr] = bv.w;
        __syncthreads();
        #pragma unroll
        for (int k = 0; k < 16; k++) {
            float4 a4 = *(const float4*)&As[k][tm * 4];
            float4 b4 = *(const float4*)&Bs[k][tn * 4];
            float am[4] = {a4.x, a4.y, a4.z, a4.w};
            float bn[4] = {b4.x, b4.y, b4.z, b4.w};
            #pragma unroll
            for (int i = 0; i < 4; i++)
                #pragma unroll
                for (int j = 0; j < 4; j++)
                    acc[i][j] = fmaf(am[i], bn[j], acc[i][j]);
        }
        __syncthreads();
    }
    #pragma unroll
    for (int i = 0; i < 4; i++) {
        int m = m0 + tm * 4 + i;
        #pragma unroll
        for (int j = 0; j < 4; j++) {
            int n = n0 + tn * 4 + j;
            if (n >= N) continue;
            float v = acc[i][j];
            if (EPI == 1) {
                v = softplus_fast(v + aux[n]);
            }
            st1(&C[(size_t)m * ldc + n], v);
        }
    }
}

// ---------------- Depthwise causal conv (4 taps) + SiLU ----------------------
// 8 channels/thread, 16B loads; weights tap-major bf16 (one 16B load per tap).
__global__ __launch_bounds__(256) void conv_silu_kernel(
    const bf16* __restrict__ xz, const bf16* __restrict__ cwt,
    const float* __restrict__ cb, bf16* __restrict__ xc)
{
    int idx = blockIdx.x * 256 + threadIdx.x;   // R*DI/8 threads
    int d8 = idx & (DI / 8 - 1);                // 0..255
    int bl = idx >> 8;                          // 0..8191
    int l = bl & (LL - 1);
    int d0 = d8 * 8;
    float4 b0 = *(const float4*)(cb + d0);
    float4 b1 = *(const float4*)(cb + d0 + 4);
    float acc[8] = {b0.x, b0.y, b0.z, b0.w, b1.x, b1.y, b1.z, b1.w};
    #pragma unroll
    for (int k = 0; k < 4; k++) {
        if (l - 3 + k < 0) continue;
        bf16x8 xv = *(const bf16x8*)(xz + (size_t)(bl - 3 + k) * (2 * DI) + d0);
        bf16x8 wv = *(const bf16x8*)(cwt + k * DI + d0);
        #pragma unroll
        for (int j = 0; j < 8; j++)
            acc[j] = fmaf(b2f((bf16)xv[j]), b2f((bf16)wv[j]), acc[j]);
    }
    bf16x8 o;
    #pragma unroll
    for (int j = 0; j < 8; j++)
        o[j] = (short)f2b(acc[j] / (1.f + __expf(-acc[j])));
    *(bf16x8*)(xc + (size_t)bl * DI + d0) = o;
}

// ---------------- Chunked selective scan, thread-per-channel -----------------
__global__ __launch_bounds__(256) void scan_part1(
    const float* __restrict__ xdbl, const bf16* __restrict__ dty,
    const bf16* __restrict__ xc, const float* __restrict__ A_log,
    float* __restrict__ P, float* __restrict__ S)
{
    __shared__ bf16 sdt[TT][TCH];
    __shared__ bf16 su[TT][TCH];
    __shared__ alignas(16) float sBC[TT][32];
    int bid = blockIdx.x;
    int cg = bid & 7;                 // DI/TCH = 8
    int c  = (bid >> 3) & (NC - 1);
    int b  = bid >> 7;
    int d0 = cg * TCH;
    int tid = threadIdx.x;
    int w = tid >> 6, l = tid & 63;
    int lrow = l >> 5, lcol = (l & 31) * 8;
    int brow = l >> 3, bcol = (l & 7) * 4;
    int d = d0 + tid;

    float Ads[16];
    #pragma unroll
    for (int q = 0; q < 4; q++) {
        float4 a4 = *(const float4*)&A_log[(size_t)d * DS + q * 4];
        Ads[q*4+0] = -__expf(a4.x); Ads[q*4+1] = -__expf(a4.y);
        Ads[q*4+2] = -__expf(a4.z); Ads[q*4+3] = -__expf(a4.w);
    }
    float h[16], p[16];
    #pragma unroll
    for (int s = 0; s < 16; s++) { h[s] = 0.f; p[s] = 1.f; }

    const size_t rowbase = (size_t)b * LL + c * CHUNK;
    for (int t0 = 0; t0 < CHUNK; t0 += TT) {
        #pragma unroll
        for (int pp = 0; pp < 4; pp++) {
            int r0 = (pp * 4 + w) * 2;
            size_t grow = rowbase + t0 + r0 + lrow;
            gld_lds16(dty + grow * DI + d0 + lcol, &sdt[r0][0]);
            gld_lds16(xc  + grow * DI + d0 + lcol, &su[r0][0]);
        }
        gld_lds16(xdbl + (rowbase + t0 + w * 8 + brow) * 96 + DTR + bcol,
                  &sBC[w * 8][0]);
        __syncthreads();
        for (int t = 0; t < TT; t++) {
            float dtv = b2f(sdt[t][tid]);
            float uv  = b2f(su[t][tid]);
            float tmp = dtv * uv;
            const float4* bc = (const float4*)&sBC[t][0];
            float4 B0 = bc[0], B1 = bc[1], B2 = bc[2], B3 = bc[3];
            float Bv[16] = {B0.x,B0.y,B0.z,B0.w, B1.x,B1.y,B1.z,B1.w,
                            B2.x,B2.y,B2.z,B2.w, B3.x,B3.y,B3.z,B3.w};
            #pragma unroll
            for (int s = 0; s < 16; s++) {
                float dA = __expf(dtv * Ads[s]);
                h[s] = dA * h[s] + tmp * Bv[s];
                p[s] *= dA;
            }
        }
        __syncthreads();
    }
    size_t o = ((size_t)(b * NC + c) * DI + d) * DS;
    #pragma unroll
    for (int q = 0; q < 4; q++) {
        *(float4*)&P[o + q*4] = make_float4(p[q*4], p[q*4+1], p[q*4+2], p[q*4+3]);
        *(float4*)&S[o + q*4] = make_float4(h[q*4], h[q*4+1], h[q*4+2], h[q*4+3]);
    }
}

__global__ __launch_bounds__(256) void scan_combine(
    const float* __restrict__ P, float* __restrict__ S)
{
    int g = blockIdx.x * 256 + threadIdx.x;   // B*DI*DS threads
    int b = g >> 15;                          // DI*DS = 32768
    int rem = g & 32767;
    float h = 0.f;
    #pragma unroll
    for (int c = 0; c < NC; c++) {
        size_t o = ((size_t)(b * NC + c) << 15) + rem;
        float p = P[o], sv = S[o];
        S[o] = h;                             // h_in for chunk c
        h = p * h + sv;
    }
}

__global__ __launch_bounds__(256) void scan_part2(
    const float* __restrict__ xdbl, bf16* __restrict__ dty,
    const bf16* __restrict__ xc, const bf16* __restrict__ xz,
    const float* __restrict__ A_log, const float* __restrict__ Dp,
    const float* __restrict__ Hin)
{
    __shared__ bf16 sdt[TT][TCH];
    __shared__ bf16 su[TT][TCH];
    __shared__ bf16 sz[TT][TCH];
    __shared__ alignas(16) float sBC[TT][32];
    int bid = blockIdx.x;
    int cg = bid & 7;
    int c  = (bid >> 3) & (NC - 1);
    int b  = bid >> 7;
    int d0 = cg * TCH;
    int tid = threadIdx.x;
    int w = tid >> 6, l = tid & 63;
    int lrow = l >> 5, lcol = (l & 31) * 8;
    int brow = l >> 3, bcol = (l & 7) * 4;
    int d = d0 + tid;

    float Ads[16];
    #pragma unroll
    for (int q = 0; q < 4; q++) {
        float4 a4 = *(const float4*)&A_log[(size_t)d * DS + q * 4];
        Ads[q*4+0] = -__expf(a4.x); Ads[q*4+1] = -__expf(a4.y);
        Ads[q*4+2] = -__expf(a4.z); Ads[q*4+3] = -__expf(a4.w);
    }
    float h[16];
    size_t ho = ((size_t)(b * NC + c) * DI + d) * DS;
    #pragma unroll
    for (int q = 0; q < 4; q++) {
        float4 hv = *(const float4*)&Hin[ho + q*4];
        h[q*4] = hv.x; h[q*4+1] = hv.y; h[q*4+2] = hv.z; h[q*4+3] = hv.w;
    }
    float dpd = Dp[d];

    const size_t rowbase = (size_t)b * LL + c * CHUNK;
    for (int t0 = 0; t0 < CHUNK; t0 += TT) {
        #pragma unroll
        for (int pp = 0; pp < 4; pp++) {
            int r0 = (pp * 4 + w) * 2;
            size_t grow = rowbase + t0 + r0 + lrow;
            gld_lds16(dty + grow * DI + d0 + lcol, &sdt[r0][0]);
            gld_lds16(xc  + grow * DI + d0 + lcol, &su[r0][0]);
            gld_lds16(xz  + grow * (2 * DI) + DI + d0 + lcol, &sz[r0][0]);
        }
        gld_lds16(xdbl + (rowbase + t0 + w * 8 + brow) * 96 + DTR + bcol,
                  &sBC[w * 8][0]);
        __syncthreads();
        for (int t = 0; t < TT; t++) {
            float dtv = b2f(sdt[t][tid]);
            float uv  = b2f(su[t][tid]);
            float tmp = dtv * uv;
            const float4* bc = (const float4*)&sBC[t][0];
            float4 B0 = bc[0], B1 = bc[1], B2 = bc[2], B3 = bc[3];
            float4 C0 = bc[4], C1 = bc[5], C2 = bc[6], C3 = bc[7];
            float Bv[16] = {B0.x,B0.y,B0.z,B0.w, B1.x,B1.y,B1.z,B1.w,
                            B2.x,B2.y,B2.z,B2.w, B3.x,B3.y,B3.z,B3.w};
            float Cv[16] = {C0.x,C0.y,C0.z,C0.w, C1.x,C1.y,C1.z,C1.w,
                            C2.x,C2.y,C2.z,C2.w, C3.x,C3.y,C3.z,C3.w};
            float y = 0.f;
            #pragma unroll
            for (int s = 0; s < 16; s++) {
                float dA = __expf(dtv * Ads[s]);
                h[s] = dA * h[s] + tmp * Bv[s];
                y = fmaf(h[s], Cv[s], y);
            }
            float zv = b2f(sz[t][tid]);
            float yo = (y + uv * dpd) * (zv / (1.f + __expf(-zv)));
            dty[(rowbase + t0 + t) * DI + d] = f2b(yo);
        }
        __syncthreads();
    }
}

// ---------------- Monolithic scan (fallback when ws is small) ----------------
__global__ __launch_bounds__(256) void scan_mono(
    const float* __restrict__ xdbl, bf16* __restrict__ dty,
    const bf16* __restrict__ xc, const bf16* __restrict__ xz,
    const float* __restrict__ A_log, const float* __restrict__ Dp)
{
    const int TC = 64;
    int b = blockIdx.x >> 7;
    int dblk = blockIdx.x & 127;
    int d0 = dblk * 16;
    int tid = threadIdx.x;
    int s = tid & 15;
    int dg = tid >> 4;
    int d = d0 + dg;
    float Ads = -__expf(A_log[(size_t)d * DS + s]);
    float h = 0.f;
    __shared__ float sdt[TC][16], su[TC][16], sB[TC][16], sC[TC][16], sy[TC][16];
    const size_t rowbase = (size_t)b * LL;
    int wi = tid >> 2;
    int wj = (tid & 3) * 4;
    float4 dpv = *(const float4*)(Dp + d0 + wj);
    for (int t0 = 0; t0 < LL; t0 += TC) {
        {
            size_t g = (rowbase + t0 + wi) * (size_t)DI + d0 + wj;
            *(float4*)&sdt[wi][wj] = ld4(dty + g);
            *(float4*)&su[wi][wj]  = ld4(xc + g);
        }
        #pragma unroll
        for (int r = 0; r < 4; r++) {
            int i = (tid >> 4) + r * 16;
            size_t g = (rowbase + t0 + i) * 96;
            sB[i][s] = xdbl[g + DTR + s];
            sC[i][s] = xdbl[g + DTR + DS + s];
        }
        __syncthreads();
        for (int i = 0; i < TC; i++) {
            float dtv = sdt[i][dg];
            float dA = __expf(dtv * Ads);
            h = dA * h + dtv * su[i][dg] * sB[i][s];
            float yp = h * sC[i][s];
            yp += __shfl_xor(yp, 1);
            yp += __shfl_xor(yp, 2);
            yp += __shfl_xor(yp, 4);
            yp += __shfl_xor(yp, 8);
            if (s == 0) sy[i][dg] = yp;
        }
        __syncthreads();
        {
            size_t g  = (rowbase + t0 + wi) * (size_t)DI + d0 + wj;
            size_t gz = (rowbase + t0 + wi) * (size_t)(2 * DI) + DI + d0 + wj;
            float4 zv = ld4(xz + gz);
            float4 yv = *(const float4*)&sy[wi][wj];
            float4 uv = *(const float4*)&su[wi][wj];
            ushort4 o;
            o.x = f2b((yv.x + uv.x * dpv.x) * (zv.x / (1.f + __expf(-zv.x))));
            o.y = f2b((yv.y + uv.y * dpv.y) * (zv.y / (1.f + __expf(-zv.y))));
            o.z = f2b((yv.z + uv.z * dpv.z) * (zv.z / (1.f + __expf(-zv.z))));
            o.w = f2b((yv.w + uv.w * dpv.w) * (zv.w / (1.f + __expf(-zv.w))));
            *(ushort4*)(dty + g) = o;
        }
        __syncthreads();
    }
}

// ---------------- slow conv (fallback path: f32 weights, 4 ch/thread) --------
__global__ __launch_bounds__(256) void conv_silu_slow(
    const bf16* __restrict__ xz, const float* __restrict__ cw,
    const float* __restrict__ cb, bf16* __restrict__ xc)
{
    int idx = blockIdx.x * 256 + threadIdx.x;
    int d4 = idx & (DI / 4 - 1);
    int bl = idx >> 9;
    int l = bl & (LL - 1);
    int d0 = d4 * 4;
    float4 bias = *(const float4*)(cb + d0);
    float acc[4] = {bias.x, bias.y, bias.z, bias.w};
    #pragma unroll
    for (int k = 0; k < 4; k++) {
        if (l - 3 + k < 0) continue;
        float4 xv = ld4(xz + (size_t)(bl - 3 + k) * (2 * DI) + d0);
        acc[0] = fmaf(xv.x, cw[(d0 + 0) * 4 + k], acc[0]);
        acc[1] = fmaf(xv.y, cw[(d0 + 1) * 4 + k], acc[1]);
        acc[2] = fmaf(xv.z, cw[(d0 + 2) * 4 + k], acc[2]);
        acc[3] = fmaf(xv.w, cw[(d0 + 3) * 4 + k], acc[3]);
    }
    ushort4 o;
    o.x = f2b(acc[0] / (1.f + __expf(-acc[0])));
    o.y = f2b(acc[1] / (1.f + __expf(-acc[1])));
    o.z = f2b(acc[2] / (1.f + __expf(-acc[2])));
    o.w = f2b(acc[3] / (1.f + __expf(-acc[3])));
    *(ushort4*)(xc + (size_t)bl * DI + d0) = o;
}

// ---------------------------------------------------------------------------
extern "C" void kernel_launch(void* const* d_in, const int* in_sizes, int n_in,
                              void* d_out, int out_size, void* d_ws, size_t ws_size,
                              hipStream_t stream)
{
    const float* x      = (const float*)d_in[0];
    const float* ln_w   = (const float*)d_in[1];
    const float* ln_b   = (const float*)d_in[2];
    const float* W_in   = (const float*)d_in[3];
    const float* conv_w = (const float*)d_in[4];
    const float* conv_b = (const float*)d_in[5];
    const float* W_x    = (const float*)d_in[6];
    const float* W_dt   = (const float*)d_in[7];
    const float* b_dt   = (const float*)d_in[8];
    const float* A_log  = (const float*)d_in[9];
    const float* Dp     = (const float*)d_in[10];
    const float* W_out  = (const float*)d_in[11];
    float* out = (float*)d_out;

    const size_t R = (size_t)BB * LL;   // 8192 rows

    // ws: xz bf16 64MB | dty bf16 32MB | xdbl f32 3MB | P,S f32 8MB each
    //     | W_x_b (128 rows pad) | W_dt_b | dtr bf16 | cwt bf16 [4][DI]
    bf16*  xz    = (bf16*)d_ws;                    // R * 2*DI
    bf16*  dty   = xz + R * 2 * DI;                // R * DI
    float* xdbl  = (float*)(dty + R * DI);         // R * 96
    float* Pbuf  = xdbl + R * 96;                  // B*NC*DI*DS
    float* Sbuf  = Pbuf + (size_t)BB * NC * DI * DS;
    bf16*  W_x_b  = (bf16*)(Sbuf + (size_t)BB * NC * DI * DS);  // 128*DI (96 used)
    bf16*  W_dt_b = W_x_b + 128 * DI;              // DI * DTR
    bf16*  dtr    = W_dt_b + DI * DTR;             // R * DTR
    bf16*  cwt    = dtr + R * DTR;                 // 4 * DI
    const size_t ws_need = (size_t)((char*)(cwt + 4 * DI) - (char*)d_ws);
    const bool fast = ws_size >= ws_need;

    bf16*  W_in_b  = dty;   // dead before dt-gemm writes dty
    bf16*  W_out_b = xz;    // converted AFTER scan consumed z

    bf16* xn = (bf16*)d_out;
    bf16* xc = (bf16*)d_out;

    // 0. weight converts
    f2b_kernel<<<(2 * DI * DM / 4) / 256, 256, 0, stream>>>(W_in, W_in_b, 2 * DI * DM / 4);
    if (fast) {
        f2b_kernel<<<(96 * DI / 4 + 255) / 256, 256, 0, stream>>>(W_x, W_x_b, 96 * DI / 4);
        f2b_kernel<<<(DI * DTR / 4 + 255) / 256, 256, 0, stream>>>(W_dt, W_dt_b, DI * DTR / 4);
        convw_transpose<<<DI / 256, 256, 0, stream>>>(conv_w, cwt);
    }

    // 1. LayerNorm -> xn bf16
    ln_kernel<<<(int)R, 256, 0, stream>>>(x, ln_w, ln_b, xn);

    // 2. in_proj (MFMA): xz[8192,4096] = xn @ W_in^T
    gemm_mfma<0, bf16><<<dim3(2 * DI / 128, R / 128), 256, 0, stream>>>(
        xn, DM, W_in_b, DM, xz, 2 * DI, DM, nullptr);

    if (fast) {
        // 3. conv + SiLU -> xc (8 ch/thread, tap-major bf16 weights)
        conv_silu_kernel<<<(int)(R * DI / 8 / 256), 256, 0, stream>>>(
            xz, cwt, conv_b, xc);
        // 4a. x_proj MFMA -> xdbl f32 + dtr bf16
        xproj_mfma<<<(int)(R / 32), 256, 0, stream>>>(xc, W_x_b, xdbl, dtr);
        // 4b. dt = softplus(dtr @ W_dt^T + b_dt) -> dty bf16 (MFMA, K=64)
        gemm_mfma<1, bf16><<<dim3(DI / 128, R / 128), 256, 0, stream>>>(
            dtr, DTR, W_dt_b, DTR, dty, DI, DTR, b_dt);
        // 5. chunked scan
        scan_part1<<<BB * NC * (DI / TCH), 256, 0, stream>>>(
            xdbl, dty, xc, A_log, Pbuf, Sbuf);
        scan_combine<<<BB * DI * DS / 256, 256, 0, stream>>>(Pbuf, Sbuf);
        scan_part2<<<BB * NC * (DI / TCH), 256, 0, stream>>>(
            xdbl, dty, xc, xz, A_log, Dp, Sbuf);
    } else {
        // fallback: slow conv + f32 small GEMMs + monolithic scan
        conv_silu_slow<<<(int)(R * DI / 4 / 256), 256, 0, stream>>>(
            xz, conv_w, conv_b, xc);
        gemm_nt<0><<<dim3(2, R / 64), 256, 0, stream>>>(
            xc, DI, W_x, DI, xdbl, 96, (int)R, 96, DI, nullptr);
        gemm_nt<1><<<dim3(DI / 64, R / 64), 256, 0, stream>>>(
            xdbl, 96, W_dt, DTR, dty, DI, (int)R, DI, DTR, b_dt);
        scan_mono<<<BB * (DI / 16), 256, 0, stream>>>(
            xdbl, dty, xc, xz, A_log, Dp);
    }

    // 5b. weight convert (W_out) into xz head (z now dead)
    f2b_kernel<<<(DM * DI / 4) / 256, 256, 0, stream>>>(W_out, W_out_b, DM * DI / 4);

    // 6. out_proj (MFMA) + residual: out = y @ W_out^T + x
    gemm_mfma<2, float><<<dim3(DM / 128, R / 128), 256, 0, stream>>>(
        dty, DI, W_out_b, DI, out, DM, DI, x);
}